// Round 5
// baseline (340.540 us; speedup 1.0000x reference)
//
#include <hip/hip_runtime.h>
#include <hip/hip_bf16.h>

#define EPSF 1e-5f

typedef __bf16 bf16x8 __attribute__((ext_vector_type(8)));
typedef float f32x4 __attribute__((ext_vector_type(4)));

__device__ __forceinline__ float softplus_f(float x) {
  return fmaxf(x, 0.0f) + log1pf(expf(-fabsf(x)));
}

__device__ __forceinline__ unsigned short f2bf_bits(float f) {
  union { float f; unsigned int u; } v; v.f = f;
  unsigned int u = v.u;
  unsigned int lsb = (u >> 16) & 1u;
  u += 0x7fffu + lsb;  // round-to-nearest-even
  return (unsigned short)(u >> 16);
}

__device__ __forceinline__ void gl2lds16(const void* g, void* l) {
  __builtin_amdgcn_global_load_lds((const __attribute__((address_space(1))) void*)g,
                                   (__attribute__((address_space(3))) void*)l,
                                   16, 0, 0);
}

// ---------------- graph prep ----------------
__global__ __launch_bounds__(256) void k_wsum(const float* __restrict__ adj,
                                              const int* __restrict__ eidx,
                                              float* __restrict__ wsum) {
  __shared__ float part[256];
  int g = blockIdx.x;
  int t = threadIdx.x;
  int el = t & 7;
  int e = g * 8 + el;
  int s = eidx[e], d = eidx[512 + e];
  int boff = t >> 3;
  float acc = 0.f;
#pragma unroll
  for (int i = 0; i < 8; i++) {
    int b = boff + 32 * i;
    int base = b * 4096;
    float w1 = adj[base + s * 64 + d];
    float w2 = adj[base + d * 64 + s];
    acc += fmaxf(w1, w2);
  }
  part[t] = acc;
  __syncthreads();
  if (t < 8) {
    float sum = 0.f;
    for (int i = t; i < 256; i += 8) sum += part[i];
    wsum[g * 8 + t] = sum;
  }
}

__global__ __launch_bounds__(512) void k_S(const int* __restrict__ eidx,
                                           const float* __restrict__ wsum,
                                           float* __restrict__ S) {
  __shared__ float deg[64];
  __shared__ float Ssh[4096];
  int t = threadIdx.x;
  if (t < 64) deg[t] = 0.f;
  for (int i = t; i < 4096; i += 512) Ssh[i] = 0.f;
  __syncthreads();
  int s = eidx[t], d = eidx[512 + t];
  float w = wsum[t];
  atomicAdd(&deg[s], w);
  __syncthreads();
  float ds = deg[s], dd = deg[d];
  float dis = ds > 0.f ? 1.0f / sqrtf(ds) : 0.f;
  float did = dd > 0.f ? 1.0f / sqrtf(dd) : 0.f;
  float coef = -dis * w * did;
  atomicAdd(&Ssh[d * 64 + s], coef);
  __syncthreads();
  for (int i = t; i < 4096; i += 512) S[i] = Ssh[i];
}

__global__ __launch_bounds__(256) void k_h1(const float* __restrict__ S,
                                            const float* __restrict__ x,
                                            float* __restrict__ h1) {
  int idx = blockIdx.x * 256 + threadIdx.x;
  if (idx >= 64 * 657) return;
  int i = idx / 657, f = idx - i * 657;
  float acc = 0.f;
#pragma unroll 16
  for (int j = 0; j < 64; j++) acc += S[i * 64 + j] * x[j * 657 + f];
  h1[idx] = acc;
}

__global__ __launch_bounds__(256) void k_h2(const float* __restrict__ S,
                                            const float* __restrict__ h1,
                                            float* __restrict__ h2) {
  int idx = blockIdx.x * 256 + threadIdx.x;
  if (idx >= 64 * 657) return;
  int i = idx / 657, f = idx - i * 657;
  float acc = 0.f;
#pragma unroll 16
  for (int j = 0; j < 64; j++) acc += S[i * 64 + j] * h1[j * 657 + f];
  h2[idx] = 2.f * acc;
}

// pack h12[64][1344] bf16 = [h1 | pad | h2 | pad]
__global__ __launch_bounds__(256) void k_pack_h12(const float* __restrict__ h1,
                                                  const float* __restrict__ h2,
                                                  unsigned short* __restrict__ h12) {
  int idx = blockIdx.x * 256 + threadIdx.x;  // 64*1344 = 86016
  int i = idx / 1344, k = idx - i * 1344;
  float v = 0.f;
  if (k < 657) v = h1[i * 657 + k];
  else if (k >= 672 && k < 1329) v = h2[i * 657 + (k - 672)];
  h12[idx] = f2bf_bits(v);
}

// BThc[n][gk] = gk<672 ? W1[gk][n] : W2[gk-672][n]  (bf16, zero-padded), 768 x 1344
__global__ __launch_bounds__(256) void k_bhc(const float* __restrict__ cheb_w,
                                             unsigned short* __restrict__ bt) {
  __shared__ float tile[64][65];
  int k0 = blockIdx.x * 64;  // 21 tiles
  int n0 = blockIdx.y * 64;  // 12 tiles
  int t = threadIdx.x;
  const float* W1 = cheb_w + 657 * 657;
  const float* W2 = cheb_w + 2 * 657 * 657;
#pragma unroll
  for (int i = 0; i < 16; i++) {
    int idx = i * 256 + t;
    int kk = idx >> 6, nn = idx & 63;
    int gk = k0 + kk, n = n0 + nn;
    float v = 0.f;
    if (n < 657) {
      if (gk < 672) {
        if (gk < 657) v = W1[gk * 657 + n];
      } else {
        int k2 = gk - 672;
        if (k2 < 657) v = W2[k2 * 657 + n];
      }
    }
    tile[kk][nn] = v;
  }
  __syncthreads();
#pragma unroll
  for (int i = 0; i < 16; i++) {
    int idx = i * 256 + t;
    int nn = idx >> 6, kk = idx & 63;
    int gk = k0 + kk, n = n0 + nn;
    bt[(size_t)n * 1344 + gk] = f2bf_bits(tile[kk][nn]);
  }
}

// hc(64x672 fp32, pre-zeroed) += h12(64x1344) @ BThc^T ; split-K via blockIdx.y
__global__ __launch_bounds__(256) void k_gemm_hc(
    const unsigned short* __restrict__ A,    // 64 x 1344 bf16
    const unsigned short* __restrict__ Bt,   // 768 x 1344 bf16
    float* __restrict__ hc) {                // 64 x 672 fp32
  __shared__ __align__(16) unsigned short As[64 * 32];
  __shared__ __align__(16) unsigned short Bs[128 * 32];
  const int nBase = blockIdx.x * 128;       // 6 tiles
  const int kc0 = blockIdx.y * 192;         // 7 splits x 6 iters
  const int tid = threadIdx.x;
  const int wave = tid >> 6, lane = tid & 63;
  const int wn = wave * 32;
  const int q = lane >> 4, r = lane & 15;
  f32x4 acc[4][2] = {};
  for (int kt = 0; kt < 6; kt++) {
    int k0 = kc0 + kt * 32;
    {
      int c = tid;
      int row = c >> 2, kg = (c & 3) * 8;
      gl2lds16(A + (size_t)row * 1344 + k0 + kg, &As[c * 8]);
    }
#pragma unroll
    for (int i = 0; i < 2; i++) {
      int c = i * 256 + tid;
      int row = c >> 2, kg = (c & 3) * 8;
      gl2lds16(Bt + (size_t)(nBase + row) * 1344 + k0 + kg, &Bs[c * 8]);
    }
    __syncthreads();
    bf16x8 a[4], b[2];
#pragma unroll
    for (int mi = 0; mi < 4; mi++)
      a[mi] = *(const bf16x8*)&As[(mi * 16 + r) * 32 + q * 8];
#pragma unroll
    for (int ni = 0; ni < 2; ni++)
      b[ni] = *(const bf16x8*)&Bs[(wn + ni * 16 + r) * 32 + q * 8];
#pragma unroll
    for (int mi = 0; mi < 4; mi++)
#pragma unroll
      for (int ni = 0; ni < 2; ni++)
        acc[mi][ni] = __builtin_amdgcn_mfma_f32_16x16x32_bf16(a[mi], b[ni], acc[mi][ni], 0, 0, 0);
    __syncthreads();
  }
#pragma unroll
  for (int ni = 0; ni < 2; ni++) {
    int f = nBase + wn + ni * 16 + r;
    if (f >= 672) continue;
#pragma unroll
    for (int mi = 0; mi < 4; mi++)
#pragma unroll
      for (int p = 0; p < 4; p++) {
        int row = mi * 16 + q * 4 + p;
        atomicAdd(&hc[row * 672 + f], acc[mi][ni][p]);
      }
  }
}

// xf_pad: 16384 x 672 bf16, packed-pair stores (uint = 2 bf16)
__global__ __launch_bounds__(256) void k_pad(const float* __restrict__ x,
                                             unsigned int* __restrict__ xp) {
  int idx = blockIdx.x * 256 + threadIdx.x;  // 16384*336
  int rr = idx / 336, u = idx - rr * 336;
  int c0 = u * 2;
  float a = (c0 < 657) ? x[rr * 657 + c0] : 0.f;
  float b = (c0 + 1 < 657) ? x[rr * 657 + c0 + 1] : 0.f;
  xp[idx] = ((unsigned int)f2bf_bits(b) << 16) | (unsigned int)f2bf_bits(a);
}

// WdT_pad[n][k] = W0[k][n] - W2[k][n], 768 x 672 bf16, LDS-tiled transpose
__global__ __launch_bounds__(256) void k_wdt(const float* __restrict__ cheb_w,
                                             unsigned short* __restrict__ wt) {
  __shared__ float tile[64][65];
  int k0 = blockIdx.x * 64;
  int n0 = blockIdx.y * 64;
  int t = threadIdx.x;
  const float* W2 = cheb_w + 2 * 657 * 657;
#pragma unroll
  for (int i = 0; i < 16; i++) {
    int idx = i * 256 + t;
    int kk = idx >> 6, nn = idx & 63;
    int k = k0 + kk, n = n0 + nn;
    float v = 0.f;
    if (k < 657 && n < 657) v = cheb_w[k * 657 + n] - W2[k * 657 + n];
    tile[kk][nn] = v;
  }
  __syncthreads();
#pragma unroll
  for (int i = 0; i < 16; i++) {
    int idx = i * 256 + t;
    int nn = idx >> 6, kk = idx & 63;
    int k = k0 + kk, n = n0 + nn;
    if (k < 672 && n < 768) wt[n * 672 + k] = f2bf_bits(tile[kk][nn]);
  }
}

// Wt_pad[o][n*672+f] = fc1_w[n*657+f][o] (f<657), else 0.  256 x 43008 bf16.
__global__ __launch_bounds__(256) void k_wt1(const float* __restrict__ W,
                                             unsigned short* __restrict__ Wt) {
  __shared__ float tile[64][65];
  int k0 = blockIdx.x * 64;  // 672 blocks over 43008
  int n0 = blockIdx.y * 64;  // 4 blocks over 256
  int t = threadIdx.x;
#pragma unroll
  for (int i = 0; i < 16; i++) {
    int idx = i * 256 + t;
    int kk = idx >> 6, nn = idx & 63;
    int kg = k0 + kk;
    int nnode = kg / 672, f = kg - nnode * 672;
    float v = 0.f;
    if (f < 657) v = W[(size_t)(nnode * 657 + f) * 256 + n0 + nn];
    tile[kk][nn] = v;
  }
  __syncthreads();
#pragma unroll
  for (int i = 0; i < 16; i++) {
    int idx = i * 256 + t;
    int nn = idx >> 6, kk = idx & 63;
    Wt[(size_t)(n0 + nn) * 43008 + k0 + kk] = f2bf_bits(tile[kk][nn]);
  }
}

// ---------------- main GEMM: out1 = bn1(softplus(xf@Wd + cheb_b [+ hc rows<64])) ----------------
// BK=96 (7 iters), LDS-bounce epilogue, out1 stride 672.
__global__ __launch_bounds__(256) void k_gemm_main(
    const unsigned short* __restrict__ Ap,   // 16384 x 672 bf16
    const unsigned short* __restrict__ BT,   // 768 x 672 bf16
    const float* __restrict__ hc,            // 64 x 672
    const float* __restrict__ cheb_b,
    const float* __restrict__ bn1,           // 4 x 657
    unsigned short* __restrict__ out1) {     // 16384 x 672 bf16 (padded)
  __shared__ __align__(16) unsigned short lds[2 * 128 * 96];  // 48 KB
  unsigned short* As = lds;                 // 128 x 96
  unsigned short* Bs = lds + 128 * 96;      // 128 x 96
  const int mBase = blockIdx.x * 128;
  const int nBase = blockIdx.y * 128;
  const int tid = threadIdx.x;
  const int wave = tid >> 6, lane = tid & 63;
  const int wm = (wave >> 1) * 64, wn = (wave & 1) * 64;
  const int q = lane >> 4, r = lane & 15;
  f32x4 acc[4][4] = {};
  for (int k0 = 0; k0 < 672; k0 += 96) {
#pragma unroll
    for (int i = 0; i < 6; i++) {
      int c = i * 256 + tid;                // 1536 chunks of 16B per tile
      int row = c / 12, kg = (c % 12) * 8;
      gl2lds16(Ap + (size_t)(mBase + row) * 672 + k0 + kg, &As[c * 8]);
      gl2lds16(BT + (size_t)(nBase + row) * 672 + k0 + kg, &Bs[c * 8]);
    }
    __syncthreads();
#pragma unroll
    for (int kk = 0; kk < 3; kk++) {
      bf16x8 a[4], b[4];
#pragma unroll
      for (int mi = 0; mi < 4; mi++)
        a[mi] = *(const bf16x8*)&As[(wm + mi * 16 + r) * 96 + kk * 32 + q * 8];
#pragma unroll
      for (int ni = 0; ni < 4; ni++)
        b[ni] = *(const bf16x8*)&Bs[(wn + ni * 16 + r) * 96 + kk * 32 + q * 8];
#pragma unroll
      for (int mi = 0; mi < 4; mi++)
#pragma unroll
        for (int ni = 0; ni < 4; ni++)
          acc[mi][ni] = __builtin_amdgcn_mfma_f32_16x16x32_bf16(a[mi], b[ni], acc[mi][ni], 0, 0, 0);
    }
    __syncthreads();
  }
  // ---- epilogue: bn/softplus in registers, bounce through LDS, 16B stores ----
  const bool add_hc = (mBase == 0) && (wm == 0);  // wave-uniform
  unsigned short* sh = lds + wave * 4096;  // 64x64 ushort per wave (8 KB)
#pragma unroll
  for (int ni = 0; ni < 4; ni++) {
    int f = nBase + wn + ni * 16 + r;
    int fc = f < 657 ? f : 656;  // clamp param reads for pad cols
    float cb = cheb_b[fc];
    float g1 = bn1[fc], b1 = bn1[657 + fc];
    float m1 = bn1[2 * 657 + fc], v1 = bn1[3 * 657 + fc];
    float inv = 1.0f / sqrtf(v1 + EPSF);
#pragma unroll
    for (int mi = 0; mi < 4; mi++) {
#pragma unroll
      for (int p = 0; p < 4; p++) {
        int rowl = mi * 16 + q * 4 + p;
        float v = acc[mi][ni][p] + cb;
        if (add_hc) v += hc[rowl * 672 + f];
        v = softplus_f(v);
        v = g1 * (v - m1) * inv + b1;
        if (f >= 657) v = 0.f;
        sh[rowl * 64 + ni * 16 + r] = f2bf_bits(v);
      }
    }
  }
  __syncthreads();
#pragma unroll
  for (int j = 0; j < 8; j++) {
    int c = j * 64 + lane;                 // 512 chunks of 16B
    int rowl = c >> 3, seg = c & 7;
    int col = nBase + wn + seg * 8;
    if (col < 672) {
      uint4 v = *(const uint4*)&sh[rowl * 64 + seg * 8];
      *(uint4*)&out1[(size_t)(mBase + wm + rowl) * 672 + col] = v;
    }
  }
}

// ---------------- fc1 GEMM split-K: Cacc += out1(256x43008) @ Wt_pad^T ----------------
__global__ __launch_bounds__(256) void k_gemm_fc1(
    const unsigned short* __restrict__ A,    // 256 x 43008 bf16
    const unsigned short* __restrict__ Bt,   // 256 x 43008 bf16 (Wt_pad)
    float* __restrict__ Cacc) {              // 256 x 256, pre-zeroed
  __shared__ __align__(16) unsigned short As[128 * 32];
  __shared__ __align__(16) unsigned short Bs[128 * 32];
  const int mBase = blockIdx.x * 128;
  const int nBase = blockIdx.y * 128;
  const int kc0 = blockIdx.z * 512;  // 84 * 512 = 43008
  const int tid = threadIdx.x;
  const int wave = tid >> 6, lane = tid & 63;
  const int wm = (wave >> 1) * 64, wn = (wave & 1) * 64;
  const int q = lane >> 4, r = lane & 15;
  f32x4 acc[4][4] = {};
  for (int kt = 0; kt < 16; kt++) {
    int k0 = kc0 + kt * 32;
#pragma unroll
    for (int i = 0; i < 2; i++) {
      int c = i * 256 + tid;
      int row = c >> 2, kg = (c & 3) * 8;
      gl2lds16(A + (size_t)(mBase + row) * 43008 + k0 + kg, &As[c * 8]);
      gl2lds16(Bt + (size_t)(nBase + row) * 43008 + k0 + kg, &Bs[c * 8]);
    }
    __syncthreads();
    bf16x8 a[4], b[4];
#pragma unroll
    for (int mi = 0; mi < 4; mi++)
      a[mi] = *(const bf16x8*)&As[(wm + mi * 16 + r) * 32 + q * 8];
#pragma unroll
    for (int ni = 0; ni < 4; ni++)
      b[ni] = *(const bf16x8*)&Bs[(wn + ni * 16 + r) * 32 + q * 8];
#pragma unroll
    for (int mi = 0; mi < 4; mi++)
#pragma unroll
      for (int ni = 0; ni < 4; ni++)
        acc[mi][ni] = __builtin_amdgcn_mfma_f32_16x16x32_bf16(a[mi], b[ni], acc[mi][ni], 0, 0, 0);
    __syncthreads();
  }
#pragma unroll
  for (int ni = 0; ni < 4; ni++) {
    int col = nBase + wn + ni * 16 + r;
#pragma unroll
    for (int mi = 0; mi < 4; mi++)
#pragma unroll
      for (int p = 0; p < 4; p++) {
        int row = mBase + wm + mi * 16 + q * 4 + p;
        atomicAdd(&Cacc[row * 256 + col], acc[mi][ni][p]);
      }
  }
}

// ---------------- tail ----------------
__global__ __launch_bounds__(256) void k_final(
    const float* __restrict__ Cacc,
    const float* __restrict__ fc1_b,
    const float* __restrict__ bnf1,
    const float* __restrict__ fc2_w,
    const float* __restrict__ fc2_b,
    const float* __restrict__ bnf2,
    const float* __restrict__ fc3_w,
    const float* __restrict__ fc3_b,
    const float* __restrict__ bnf3,
    float* __restrict__ out) {
  __shared__ float a1[256];
  __shared__ float a2[32];
  __shared__ float z[4];
  int b = blockIdx.x, t = threadIdx.x;
  {
    float v = Cacc[b * 256 + t] + fc1_b[t];
    v = softplus_f(v);
    float g = bnf1[t], bb = bnf1[256 + t];
    float m = bnf1[512 + t], vv = bnf1[768 + t];
    a1[t] = g * (v - m) / sqrtf(vv + EPSF) + bb;
  }
  __syncthreads();
  if (t < 32) {
    float s = fc2_b[t];
#pragma unroll 8
    for (int k = 0; k < 256; k++) s += a1[k] * fc2_w[k * 32 + t];
    s = softplus_f(s);
    float g = bnf2[t], bb = bnf2[32 + t];
    float m = bnf2[64 + t], vv = bnf2[96 + t];
    a2[t] = g * (s - m) / sqrtf(vv + EPSF) + bb;
  }
  __syncthreads();
  if (t < 4) {
    float s = fc3_b[t];
#pragma unroll
    for (int k = 0; k < 32; k++) s += a2[k] * fc3_w[k * 4 + t];
    float g = bnf3[t], bb = bnf3[4 + t];
    float m = bnf3[8 + t], vv = bnf3[12 + t];
    s = g * (s - m) / sqrtf(vv + EPSF) + bb;
    z[t] = softplus_f(s);
  }
  __syncthreads();
  if (t == 0) {
    float mx = fmaxf(fmaxf(z[0], z[1]), fmaxf(z[2], z[3]));
    float e0 = expf(z[0] - mx), e1 = expf(z[1] - mx);
    float e2 = expf(z[2] - mx), e3 = expf(z[3] - mx);
    float inv = 1.0f / (e0 + e1 + e2 + e3);
    out[b * 4 + 0] = e0 * inv;
    out[b * 4 + 1] = e1 * inv;
    out[b * 4 + 2] = e2 * inv;
    out[b * 4 + 3] = e3 * inv;
  }
}

extern "C" void kernel_launch(void* const* d_in, const int* in_sizes, int n_in,
                              void* d_out, int out_size, void* d_ws, size_t ws_size,
                              hipStream_t stream) {
  const float* x      = (const float*)d_in[0];
  const float* adj    = (const float*)d_in[1];
  const int*   eidx   = (const int*)d_in[2];
  const float* cheb_w = (const float*)d_in[3];
  const float* cheb_b = (const float*)d_in[4];
  const float* fc1_w  = (const float*)d_in[5];
  const float* fc1_b  = (const float*)d_in[6];
  const float* fc2_w  = (const float*)d_in[7];
  const float* fc2_b  = (const float*)d_in[8];
  const float* fc3_w  = (const float*)d_in[9];
  const float* fc3_b  = (const float*)d_in[10];
  const float* bn1    = (const float*)d_in[11];
  const float* bnf1   = (const float*)d_in[12];
  const float* bnf2   = (const float*)d_in[13];
  const float* bnf3   = (const float*)d_in[14];

  char* ws = (char*)d_ws;
  float* S       = (float*)(ws + 0);          // 16384 B
  float* wsum    = (float*)(ws + 16384);      // 2048 B
  float* h1      = (float*)(ws + 18432);      // 168192 B
  float* h2      = (float*)(ws + 186624);     // 168192 B
  float* hc      = (float*)(ws + 354816);     // 172032 B (64 x 672 fp32)
  float* fc1_acc = (float*)(ws + 526848);     // 262144 B
  unsigned short* xpad = (unsigned short*)(ws + 788992);      // 22020096 B
  unsigned short* wdt  = (unsigned short*)(ws + 22809088);    // 1032192 B
  unsigned short* out1 = (unsigned short*)(ws + 23841280);    // 22020096 B (16384x672, end ~45.9 MB)
  // Wt_pad aliases xpad (dead after k_gemm_main): 256*43008*2 = 22020096 = xpad size exactly.
  unsigned short* Wt = xpad;
  // h12/BThc alias xpad too (consumed by k_gemm_hc before k_pad overwrites).
  unsigned short* h12  = xpad;                                      // 172032 B
  unsigned short* BThc = (unsigned short*)((char*)xpad + 172032);   // 2064384 B

  hipMemsetAsync(fc1_acc, 0, 256 * 256 * sizeof(float), stream);
  hipMemsetAsync(hc, 0, 64 * 672 * sizeof(float), stream);

  k_wsum<<<64, 256, 0, stream>>>(adj, eidx, wsum);
  k_S<<<1, 512, 0, stream>>>(eidx, wsum, S);
  k_h1<<<165, 256, 0, stream>>>(S, x, h1);
  k_h2<<<165, 256, 0, stream>>>(S, h1, h2);
  k_pack_h12<<<336, 256, 0, stream>>>(h1, h2, h12);
  k_bhc<<<dim3(21, 12), 256, 0, stream>>>(cheb_w, BThc);
  k_gemm_hc<<<dim3(6, 7), 256, 0, stream>>>(h12, BThc, hc);
  k_pad<<<21504, 256, 0, stream>>>(x, (unsigned int*)xpad);
  k_wdt<<<dim3(11, 12), 256, 0, stream>>>(cheb_w, wdt);
  k_gemm_main<<<dim3(128, 6), 256, 0, stream>>>(xpad, wdt, hc, cheb_b, bn1, out1);
  k_wt1<<<dim3(672, 4), 256, 0, stream>>>(fc1_w, Wt);
  k_gemm_fc1<<<dim3(2, 2, 84), 256, 0, stream>>>(out1, Wt, fc1_acc);
  k_final<<<256, 256, 0, stream>>>(fc1_acc, fc1_b, bnf1, fc2_w, fc2_b, bnf2,
                                   fc3_w, fc3_b, bnf3, (float*)d_out);
}

// Round 7
// 314.511 us; speedup vs baseline: 1.0828x; 1.0828x over previous
//
#include <hip/hip_runtime.h>
#include <hip/hip_bf16.h>

#define EPSF 1e-5f

typedef __bf16 bf16x8 __attribute__((ext_vector_type(8)));
typedef float f32x4 __attribute__((ext_vector_type(4)));

__device__ __forceinline__ float softplus_f(float x) {
  return fmaxf(x, 0.0f) + log1pf(expf(-fabsf(x)));
}

__device__ __forceinline__ unsigned short f2bf_bits(float f) {
  union { float f; unsigned int u; } v; v.f = f;
  unsigned int u = v.u;
  unsigned int lsb = (u >> 16) & 1u;
  u += 0x7fffu + lsb;  // round-to-nearest-even
  return (unsigned short)(u >> 16);
}

__device__ __forceinline__ void gl2lds16(const void* g, void* l) {
  __builtin_amdgcn_global_load_lds((const __attribute__((address_space(1))) void*)g,
                                   (__attribute__((address_space(3))) void*)l,
                                   16, 0, 0);
}

// ---------------- graph prep ----------------
// wsum[e] += per-block partial over 4 batches; adj tile staged in LDS (coalesced).
__global__ __launch_bounds__(256) void k_wsum(const float* __restrict__ adj,
                                              const int* __restrict__ eidx,
                                              float* __restrict__ wsum) {  // pre-zeroed
  __shared__ float A[4096];
  int g = blockIdx.x, t = threadIdx.x;
  int s0 = eidx[t], d0 = eidx[512 + t];
  int s1 = eidx[256 + t], d1 = eidx[768 + t];
  float acc0 = 0.f, acc1 = 0.f;
  for (int bb = 0; bb < 4; bb++) {
    const float* ab = adj + (size_t)(g * 4 + bb) * 4096;
#pragma unroll
    for (int i = 0; i < 16; i++) A[i * 256 + t] = ab[i * 256 + t];
    __syncthreads();
    acc0 += fmaxf(A[s0 * 64 + d0], A[d0 * 64 + s0]);
    acc1 += fmaxf(A[s1 * 64 + d1], A[d1 * 64 + s1]);
    __syncthreads();
  }
  atomicAdd(&wsum[t], acc0);
  atomicAdd(&wsum[256 + t], acc1);
}

__global__ __launch_bounds__(512) void k_S(const int* __restrict__ eidx,
                                           const float* __restrict__ wsum,
                                           float* __restrict__ S) {
  __shared__ float deg[64];
  __shared__ float Ssh[4096];
  int t = threadIdx.x;
  if (t < 64) deg[t] = 0.f;
  for (int i = t; i < 4096; i += 512) Ssh[i] = 0.f;
  __syncthreads();
  int s = eidx[t], d = eidx[512 + t];
  float w = wsum[t];
  atomicAdd(&deg[s], w);
  __syncthreads();
  float ds = deg[s], dd = deg[d];
  float dis = ds > 0.f ? 1.0f / sqrtf(ds) : 0.f;
  float did = dd > 0.f ? 1.0f / sqrtf(dd) : 0.f;
  float coef = -dis * w * did;
  atomicAdd(&Ssh[d * 64 + s], coef);
  __syncthreads();
  for (int i = t; i < 4096; i += 512) S[i] = Ssh[i];
}

// fused h1 = S@x, h2 = 2*S@h1, packed into h12[64][1344] bf16 = [h1|pad|h2|pad]
// grid 21 blocks x 32 f-cols; all compute LDS-resident.
__global__ __launch_bounds__(256) void k_h12f(const float* __restrict__ S,
                                              const float* __restrict__ x,
                                              unsigned short* __restrict__ h12) {
  __shared__ float Ss[4096];
  __shared__ float Xs[64 * 32];
  __shared__ float H1[64 * 32];
  int t = threadIdx.x;
  int f0 = blockIdx.x * 32;
#pragma unroll
  for (int i = 0; i < 16; i++) Ss[i * 256 + t] = S[i * 256 + t];
#pragma unroll
  for (int i = 0; i < 8; i++) {
    int idx = i * 256 + t;
    int j = idx >> 5, ff = idx & 31;
    int f = f0 + ff;
    Xs[idx] = (f < 657) ? x[j * 657 + f] : 0.f;
  }
  __syncthreads();
  int ff = t & 31, jg = t >> 5;  // 8 row-groups of 8
  int f = f0 + ff;
  float h1v[8];
#pragma unroll
  for (int jj = 0; jj < 8; jj++) h1v[jj] = 0.f;
  for (int j2 = 0; j2 < 64; j2++) {
    float xv = Xs[j2 * 32 + ff];
#pragma unroll
    for (int jj = 0; jj < 8; jj++) h1v[jj] += Ss[(jg * 8 + jj) * 64 + j2] * xv;
  }
#pragma unroll
  for (int jj = 0; jj < 8; jj++) {
    int j = jg * 8 + jj;
    H1[j * 32 + ff] = h1v[jj];
    if (f < 672) h12[j * 1344 + f] = f2bf_bits(f < 657 ? h1v[jj] : 0.f);
  }
  __syncthreads();
  float h2v[8];
#pragma unroll
  for (int jj = 0; jj < 8; jj++) h2v[jj] = 0.f;
  for (int j2 = 0; j2 < 64; j2++) {
    float xv = H1[j2 * 32 + ff];
#pragma unroll
    for (int jj = 0; jj < 8; jj++) h2v[jj] += Ss[(jg * 8 + jj) * 64 + j2] * xv;
  }
#pragma unroll
  for (int jj = 0; jj < 8; jj++) {
    int j = jg * 8 + jj;
    if (f < 672) h12[j * 1344 + 672 + f] = f2bf_bits(f < 657 ? 2.f * h2v[jj] : 0.f);
  }
}

// hc(64x672 fp32, pre-zeroed) += h12(64x1344) @ BThc^T ; split-K via blockIdx.y
__global__ __launch_bounds__(256) void k_gemm_hc(
    const unsigned short* __restrict__ A,    // 64 x 1344 bf16
    const unsigned short* __restrict__ Bt,   // 768 x 1344 bf16
    float* __restrict__ hc) {                // 64 x 672 fp32
  __shared__ __align__(16) unsigned short As[64 * 32];
  __shared__ __align__(16) unsigned short Bs[128 * 32];
  const int nBase = blockIdx.x * 128;       // 6 tiles
  const int kc0 = blockIdx.y * 192;         // 7 splits x 6 iters
  const int tid = threadIdx.x;
  const int wave = tid >> 6, lane = tid & 63;
  const int wn = wave * 32;
  const int q = lane >> 4, r = lane & 15;
  f32x4 acc[4][2] = {};
  for (int kt = 0; kt < 6; kt++) {
    int k0 = kc0 + kt * 32;
    {
      int c = tid;
      int row = c >> 2, kg = (c & 3) * 8;
      gl2lds16(A + (size_t)row * 1344 + k0 + kg, &As[c * 8]);
    }
#pragma unroll
    for (int i = 0; i < 2; i++) {
      int c = i * 256 + tid;
      int row = c >> 2, kg = (c & 3) * 8;
      gl2lds16(Bt + (size_t)(nBase + row) * 1344 + k0 + kg, &Bs[c * 8]);
    }
    __syncthreads();
    bf16x8 a[4], b[2];
#pragma unroll
    for (int mi = 0; mi < 4; mi++)
      a[mi] = *(const bf16x8*)&As[(mi * 16 + r) * 32 + q * 8];
#pragma unroll
    for (int ni = 0; ni < 2; ni++)
      b[ni] = *(const bf16x8*)&Bs[(wn + ni * 16 + r) * 32 + q * 8];
#pragma unroll
    for (int mi = 0; mi < 4; mi++)
#pragma unroll
      for (int ni = 0; ni < 2; ni++)
        acc[mi][ni] = __builtin_amdgcn_mfma_f32_16x16x32_bf16(a[mi], b[ni], acc[mi][ni], 0, 0, 0);
    __syncthreads();
  }
#pragma unroll
  for (int ni = 0; ni < 2; ni++) {
    int f = nBase + wn + ni * 16 + r;
    if (f >= 672) continue;
#pragma unroll
    for (int mi = 0; mi < 4; mi++)
#pragma unroll
      for (int p = 0; p < 4; p++) {
        int row = mi * 16 + q * 4 + p;
        atomicAdd(&hc[row * 672 + f], acc[mi][ni][p]);
      }
  }
}

// merged prep: pad (blocks 0..21503), wdt (21504..21635), bhc (21636..21887)
__global__ __launch_bounds__(256) void k_prep(const float* __restrict__ x,
                                              const float* __restrict__ cheb_w,
                                              unsigned int* __restrict__ xp,
                                              unsigned short* __restrict__ wt,
                                              unsigned short* __restrict__ bt) {
  __shared__ float tile[64][65];
  int bid = blockIdx.x;
  int t = threadIdx.x;
  if (bid < 21504) {
    // xf_pad: 16384 x 672 bf16, packed-pair stores
    int idx = bid * 256 + t;
    int rr = idx / 336, u = idx - rr * 336;
    int c0 = u * 2;
    float a = (c0 < 657) ? x[rr * 657 + c0] : 0.f;
    float b = (c0 + 1 < 657) ? x[rr * 657 + c0 + 1] : 0.f;
    xp[idx] = ((unsigned int)f2bf_bits(b) << 16) | (unsigned int)f2bf_bits(a);
    return;
  }
  const float* W2 = cheb_w + 2 * 657 * 657;
  if (bid < 21636) {
    // WdT_pad[n][k] = W0[k][n] - W2[k][n], 768 x 672
    int rel = bid - 21504;
    int k0 = (rel % 11) * 64, n0 = (rel / 11) * 64;
#pragma unroll
    for (int i = 0; i < 16; i++) {
      int idx = i * 256 + t;
      int kk = idx >> 6, nn = idx & 63;
      int k = k0 + kk, n = n0 + nn;
      float v = 0.f;
      if (k < 657 && n < 657) v = cheb_w[k * 657 + n] - W2[k * 657 + n];
      tile[kk][nn] = v;
    }
    __syncthreads();
#pragma unroll
    for (int i = 0; i < 16; i++) {
      int idx = i * 256 + t;
      int nn = idx >> 6, kk = idx & 63;
      int k = k0 + kk, n = n0 + nn;
      if (k < 672 && n < 768) wt[n * 672 + k] = f2bf_bits(tile[kk][nn]);
    }
    return;
  }
  {
    // BThc[n][gk] = gk<672 ? W1[gk][n] : W2[gk-672][n], 768 x 1344
    int rel = bid - 21636;
    int k0 = (rel % 21) * 64, n0 = (rel / 21) * 64;
    const float* W1 = cheb_w + 657 * 657;
#pragma unroll
    for (int i = 0; i < 16; i++) {
      int idx = i * 256 + t;
      int kk = idx >> 6, nn = idx & 63;
      int gk = k0 + kk, n = n0 + nn;
      float v = 0.f;
      if (n < 657) {
        if (gk < 672) {
          if (gk < 657) v = W1[gk * 657 + n];
        } else {
          int k2 = gk - 672;
          if (k2 < 657) v = W2[k2 * 657 + n];
        }
      }
      tile[kk][nn] = v;
    }
    __syncthreads();
#pragma unroll
    for (int i = 0; i < 16; i++) {
      int idx = i * 256 + t;
      int nn = idx >> 6, kk = idx & 63;
      int gk = k0 + kk, n = n0 + nn;
      bt[(size_t)n * 1344 + gk] = f2bf_bits(tile[kk][nn]);
    }
  }
}

// Wt_pad[o][n*672+f] = fc1_w[n*657+f][o] (f<657), else 0.  256 x 43008 bf16.
__global__ __launch_bounds__(256) void k_wt1(const float* __restrict__ W,
                                             unsigned short* __restrict__ Wt) {
  __shared__ float tile[64][65];
  int k0 = blockIdx.x * 64;  // 672 blocks over 43008
  int n0 = blockIdx.y * 64;  // 4 blocks over 256
  int t = threadIdx.x;
#pragma unroll
  for (int i = 0; i < 16; i++) {
    int idx = i * 256 + t;
    int kk = idx >> 6, nn = idx & 63;
    int kg = k0 + kk;
    int nnode = kg / 672, f = kg - nnode * 672;
    float v = 0.f;
    if (f < 657) v = W[(size_t)(nnode * 657 + f) * 256 + n0 + nn];
    tile[kk][nn] = v;
  }
  __syncthreads();
#pragma unroll
  for (int i = 0; i < 16; i++) {
    int idx = i * 256 + t;
    int nn = idx >> 6, kk = idx & 63;
    Wt[(size_t)(n0 + nn) * 43008 + k0 + kk] = f2bf_bits(tile[kk][nn]);
  }
}

// ---------------- main GEMM: out1 = bn1(softplus(xf@Wd + cheb_b [+ hc rows<64])) ----------------
// 64x128 tile, BK=32, grid (256,6)=1536 blocks (6/CU), LDS-bounce epilogue.
__global__ __launch_bounds__(256) void k_gemm_main(
    const unsigned short* __restrict__ Ap,   // 16384 x 672 bf16
    const unsigned short* __restrict__ BT,   // 768 x 672 bf16
    const float* __restrict__ hc,            // 64 x 672
    const float* __restrict__ cheb_b,
    const float* __restrict__ bn1,           // 4 x 657
    unsigned short* __restrict__ out1) {     // 16384 x 672 bf16 (padded)
  __shared__ __align__(16) unsigned short lds[8192];  // 16 KB
  unsigned short* As = lds;            // 64 x 32
  unsigned short* Bs = lds + 2048;     // 128 x 32
  const int mBase = blockIdx.x * 64;
  const int nBase = blockIdx.y * 128;
  const int tid = threadIdx.x;
  const int wave = tid >> 6, lane = tid & 63;
  const int wm = (wave & 1) * 32;      // 2x2 wave grid: each wave 32x64
  const int wn = (wave >> 1) * 64;
  const int q = lane >> 4, r = lane & 15;
  f32x4 acc[2][4] = {};
  for (int k0 = 0; k0 < 672; k0 += 32) {
    gl2lds16(Ap + (size_t)(mBase + (tid >> 2)) * 672 + k0 + (tid & 3) * 8, &As[tid * 8]);
#pragma unroll
    for (int i = 0; i < 2; i++) {
      int c = i * 256 + tid;
      gl2lds16(BT + (size_t)(nBase + (c >> 2)) * 672 + k0 + (c & 3) * 8, &Bs[c * 8]);
    }
    __syncthreads();
    bf16x8 a[2], b[4];
#pragma unroll
    for (int mi = 0; mi < 2; mi++)
      a[mi] = *(const bf16x8*)&As[(wm + mi * 16 + r) * 32 + q * 8];
#pragma unroll
    for (int ni = 0; ni < 4; ni++)
      b[ni] = *(const bf16x8*)&Bs[(wn + ni * 16 + r) * 32 + q * 8];
#pragma unroll
    for (int mi = 0; mi < 2; mi++)
#pragma unroll
      for (int ni = 0; ni < 4; ni++)
        acc[mi][ni] = __builtin_amdgcn_mfma_f32_16x16x32_bf16(a[mi], b[ni], acc[mi][ni], 0, 0, 0);
    __syncthreads();
  }
  // epilogue: bn/softplus in regs -> per-wave LDS bounce (32x64) -> 16B stores
  const bool add_hc = (mBase == 0);    // rows 0..63 all carry hc
  unsigned short* sh = lds + wave * 2048;
#pragma unroll
  for (int ni = 0; ni < 4; ni++) {
    int f = nBase + wn + ni * 16 + r;
    int fc = f < 657 ? f : 656;
    float cb = cheb_b[fc];
    float g1 = bn1[fc], b1 = bn1[657 + fc];
    float m1 = bn1[2 * 657 + fc], v1 = bn1[3 * 657 + fc];
    float inv = 1.0f / sqrtf(v1 + EPSF);
#pragma unroll
    for (int mi = 0; mi < 2; mi++) {
#pragma unroll
      for (int p = 0; p < 4; p++) {
        int lrow = mi * 16 + q * 4 + p;          // 0..31 within wave tile
        float v = acc[mi][ni][p] + cb;
        if (add_hc && f < 672) v += hc[(wm + lrow) * 672 + f];
        v = softplus_f(v);
        v = g1 * (v - m1) * inv + b1;
        if (f >= 657) v = 0.f;
        sh[lrow * 64 + ni * 16 + r] = f2bf_bits(v);
      }
    }
  }
  // each wave reads only its own bounce region; compiler inserts lgkm waits
#pragma unroll
  for (int j = 0; j < 4; j++) {
    int c = j * 64 + lane;                 // 256 chunks of 16B per wave
    int lrow = c >> 3, seg = c & 7;
    int col = nBase + wn + seg * 8;
    if (col < 672) {
      uint4 v = *(const uint4*)&sh[lrow * 64 + seg * 8];
      *(uint4*)&out1[(size_t)(mBase + wm + lrow) * 672 + col] = v;
    }
  }
}

// ---------------- fc1 GEMM split-K: Cacc += out1(256x43008) @ Wt_pad^T ----------------
__global__ __launch_bounds__(256) void k_gemm_fc1(
    const unsigned short* __restrict__ A,    // 256 x 43008 bf16
    const unsigned short* __restrict__ Bt,   // 256 x 43008 bf16 (Wt_pad)
    float* __restrict__ Cacc) {              // 256 x 256, pre-zeroed
  __shared__ __align__(16) unsigned short As[128 * 32];
  __shared__ __align__(16) unsigned short Bs[128 * 32];
  const int mBase = blockIdx.x * 128;
  const int nBase = blockIdx.y * 128;
  const int kc0 = blockIdx.z * 512;  // 84 * 512 = 43008
  const int tid = threadIdx.x;
  const int wave = tid >> 6, lane = tid & 63;
  const int wm = (wave >> 1) * 64, wn = (wave & 1) * 64;
  const int q = lane >> 4, r = lane & 15;
  f32x4 acc[4][4] = {};
  for (int kt = 0; kt < 16; kt++) {
    int k0 = kc0 + kt * 32;
#pragma unroll
    for (int i = 0; i < 2; i++) {
      int c = i * 256 + tid;
      int row = c >> 2, kg = (c & 3) * 8;
      gl2lds16(A + (size_t)(mBase + row) * 43008 + k0 + kg, &As[c * 8]);
      gl2lds16(Bt + (size_t)(nBase + row) * 43008 + k0 + kg, &Bs[c * 8]);
    }
    __syncthreads();
    bf16x8 a[4], b[4];
#pragma unroll
    for (int mi = 0; mi < 4; mi++)
      a[mi] = *(const bf16x8*)&As[(wm + mi * 16 + r) * 32 + q * 8];
#pragma unroll
    for (int ni = 0; ni < 4; ni++)
      b[ni] = *(const bf16x8*)&Bs[(wn + ni * 16 + r) * 32 + q * 8];
#pragma unroll
    for (int mi = 0; mi < 4; mi++)
#pragma unroll
      for (int ni = 0; ni < 4; ni++)
        acc[mi][ni] = __builtin_amdgcn_mfma_f32_16x16x32_bf16(a[mi], b[ni], acc[mi][ni], 0, 0, 0);
    __syncthreads();
  }
#pragma unroll
  for (int ni = 0; ni < 4; ni++) {
    int col = nBase + wn + ni * 16 + r;
#pragma unroll
    for (int mi = 0; mi < 4; mi++)
#pragma unroll
      for (int p = 0; p < 4; p++) {
        int row = mBase + wm + mi * 16 + q * 4 + p;
        atomicAdd(&Cacc[row * 256 + col], acc[mi][ni][p]);
      }
  }
}

// ---------------- tail ----------------
__global__ __launch_bounds__(256) void k_final(
    const float* __restrict__ Cacc,
    const float* __restrict__ fc1_b,
    const float* __restrict__ bnf1,
    const float* __restrict__ fc2_w,
    const float* __restrict__ fc2_b,
    const float* __restrict__ bnf2,
    const float* __restrict__ fc3_w,
    const float* __restrict__ fc3_b,
    const float* __restrict__ bnf3,
    float* __restrict__ out) {
  __shared__ float a1[256];
  __shared__ float a2[32];
  __shared__ float z[4];
  int b = blockIdx.x, t = threadIdx.x;
  {
    float v = Cacc[b * 256 + t] + fc1_b[t];
    v = softplus_f(v);
    float g = bnf1[t], bb = bnf1[256 + t];
    float m = bnf1[512 + t], vv = bnf1[768 + t];
    a1[t] = g * (v - m) / sqrtf(vv + EPSF) + bb;
  }
  __syncthreads();
  if (t < 32) {
    float s = fc2_b[t];
#pragma unroll 8
    for (int k = 0; k < 256; k++) s += a1[k] * fc2_w[k * 32 + t];
    s = softplus_f(s);
    float g = bnf2[t], bb = bnf2[32 + t];
    float m = bnf2[64 + t], vv = bnf2[96 + t];
    a2[t] = g * (s - m) / sqrtf(vv + EPSF) + bb;
  }
  __syncthreads();
  if (t < 4) {
    float s = fc3_b[t];
#pragma unroll
    for (int k = 0; k < 32; k++) s += a2[k] * fc3_w[k * 4 + t];
    float g = bnf3[t], bb = bnf3[4 + t];
    float m = bnf3[8 + t], vv = bnf3[12 + t];
    s = g * (s - m) / sqrtf(vv + EPSF) + bb;  // bn BEFORE softplus here
    z[t] = softplus_f(s);
  }
  __syncthreads();
  if (t == 0) {
    float mx = fmaxf(fmaxf(z[0], z[1]), fmaxf(z[2], z[3]));
    float e0 = expf(z[0] - mx), e1 = expf(z[1] - mx);
    float e2 = expf(z[2] - mx), e3 = expf(z[3] - mx);
    float inv = 1.0f / (e0 + e1 + e2 + e3);
    out[b * 4 + 0] = e0 * inv;
    out[b * 4 + 1] = e1 * inv;
    out[b * 4 + 2] = e2 * inv;
    out[b * 4 + 3] = e3 * inv;
  }
}

extern "C" void kernel_launch(void* const* d_in, const int* in_sizes, int n_in,
                              void* d_out, int out_size, void* d_ws, size_t ws_size,
                              hipStream_t stream) {
  const float* x      = (const float*)d_in[0];
  const float* adj    = (const float*)d_in[1];
  const int*   eidx   = (const int*)d_in[2];
  const float* cheb_w = (const float*)d_in[3];
  const float* cheb_b = (const float*)d_in[4];
  const float* fc1_w  = (const float*)d_in[5];
  const float* fc1_b  = (const float*)d_in[6];
  const float* fc2_w  = (const float*)d_in[7];
  const float* fc2_b  = (const float*)d_in[8];
  const float* fc3_w  = (const float*)d_in[9];
  const float* fc3_b  = (const float*)d_in[10];
  const float* bn1    = (const float*)d_in[11];
  const float* bnf1   = (const float*)d_in[12];
  const float* bnf2   = (const float*)d_in[13];
  const float* bnf3   = (const float*)d_in[14];

  char* ws = (char*)d_ws;
  float* S       = (float*)(ws + 0);          // 16384 B
  float* wsum    = (float*)(ws + 16384);      // 2048 B (memset region start)
  float* hc      = (float*)(ws + 18432);      // 172032 B (64 x 672 fp32)
  float* fc1_acc = (float*)(ws + 190464);     // 262144 B (memset region end)
  unsigned short* h12  = (unsigned short*)(ws + 452608);      // 172032 B
  unsigned short* xpad = (unsigned short*)(ws + 624640);      // 22020096 B
  unsigned short* wdt  = (unsigned short*)(ws + 22644736);    // 1032192 B
  unsigned short* out1 = (unsigned short*)(ws + 23676928);    // 22020096 B (end ~45.7 MB)
  // BThc aliases out1 (consumed by k_gemm_hc before k_gemm_main writes out1).
  unsigned short* BThc = out1;
  // Wt aliases xpad (written by k_wt1 after k_gemm_main consumed xpad).
  unsigned short* Wt = xpad;

  (void)hipMemsetAsync(ws + 16384, 0, 436224, stream);  // wsum + hc + fc1_acc

  k_prep<<<21888, 256, 0, stream>>>(x, cheb_w, (unsigned int*)xpad, wdt, BThc);
  k_wsum<<<64, 256, 0, stream>>>(adj, eidx, wsum);
  k_S<<<1, 512, 0, stream>>>(eidx, wsum, S);
  k_h12f<<<21, 256, 0, stream>>>(S, x, h12);
  k_gemm_hc<<<dim3(6, 7), 256, 0, stream>>>(h12, BThc, hc);
  k_gemm_main<<<dim3(256, 6), 256, 0, stream>>>(xpad, wdt, hc, cheb_b, bn1, out1);
  k_wt1<<<dim3(672, 4), 256, 0, stream>>>(fc1_w, Wt);
  k_gemm_fc1<<<dim3(2, 2, 84), 256, 0, stream>>>(out1, Wt, fc1_acc);
  k_final<<<256, 256, 0, stream>>>(fc1_acc, fc1_b, bnf1, fc2_w, fc2_b, bnf2,
                                   fc3_w, fc3_b, bnf3, (float*)d_out);
}

// Round 8
// 286.096 us; speedup vs baseline: 1.1903x; 1.0993x over previous
//
#include <hip/hip_runtime.h>
#include <hip/hip_bf16.h>

#define EPSF 1e-5f

typedef __bf16 bf16x8 __attribute__((ext_vector_type(8)));
typedef float f32x4 __attribute__((ext_vector_type(4)));

__device__ __forceinline__ float softplus_f(float x) {
  return fmaxf(x, 0.0f) + log1pf(expf(-fabsf(x)));
}

__device__ __forceinline__ float softplus_fast(float x) {
  // max(x,0) + ln(1 + e^-|x|) via native v_exp/v_log
  return fmaxf(x, 0.0f) + __logf(1.0f + __expf(-fabsf(x)));
}

__device__ __forceinline__ unsigned short f2bf_bits(float f) {
  union { float f; unsigned int u; } v; v.f = f;
  unsigned int u = v.u;
  unsigned int lsb = (u >> 16) & 1u;
  u += 0x7fffu + lsb;  // round-to-nearest-even
  return (unsigned short)(u >> 16);
}

__device__ __forceinline__ void gl2lds16(const void* g, void* l) {
  __builtin_amdgcn_global_load_lds((const __attribute__((address_space(1))) void*)g,
                                   (__attribute__((address_space(3))) void*)l,
                                   16, 0, 0);
}

// ---------------- graph prep ----------------
// wsum[e] += per-block partial over 4 batches; adj tile staged in LDS (coalesced).
__global__ __launch_bounds__(256) void k_wsum(const float* __restrict__ adj,
                                              const int* __restrict__ eidx,
                                              float* __restrict__ wsum) {  // pre-zeroed
  __shared__ float A[4096];
  int g = blockIdx.x, t = threadIdx.x;
  int s0 = eidx[t], d0 = eidx[512 + t];
  int s1 = eidx[256 + t], d1 = eidx[768 + t];
  float acc0 = 0.f, acc1 = 0.f;
  for (int bb = 0; bb < 4; bb++) {
    const float* ab = adj + (size_t)(g * 4 + bb) * 4096;
#pragma unroll
    for (int i = 0; i < 16; i++) A[i * 256 + t] = ab[i * 256 + t];
    __syncthreads();
    acc0 += fmaxf(A[s0 * 64 + d0], A[d0 * 64 + s0]);
    acc1 += fmaxf(A[s1 * 64 + d1], A[d1 * 64 + s1]);
    __syncthreads();
  }
  atomicAdd(&wsum[t], acc0);
  atomicAdd(&wsum[256 + t], acc1);
}

__global__ __launch_bounds__(512) void k_S(const int* __restrict__ eidx,
                                           const float* __restrict__ wsum,
                                           float* __restrict__ S) {
  __shared__ float deg[64];
  __shared__ float Ssh[4096];
  int t = threadIdx.x;
  if (t < 64) deg[t] = 0.f;
  for (int i = t; i < 4096; i += 512) Ssh[i] = 0.f;
  __syncthreads();
  int s = eidx[t], d = eidx[512 + t];
  float w = wsum[t];
  atomicAdd(&deg[s], w);
  __syncthreads();
  float ds = deg[s], dd = deg[d];
  float dis = ds > 0.f ? 1.0f / sqrtf(ds) : 0.f;
  float did = dd > 0.f ? 1.0f / sqrtf(dd) : 0.f;
  float coef = -dis * w * did;
  atomicAdd(&Ssh[d * 64 + s], coef);
  __syncthreads();
  for (int i = t; i < 4096; i += 512) S[i] = Ssh[i];
}

// fused h1 = S@x, h2 = 2*S@h1, packed into h12[64][1344] bf16 = [h1|pad|h2|pad]
__global__ __launch_bounds__(256) void k_h12f(const float* __restrict__ S,
                                              const float* __restrict__ x,
                                              unsigned short* __restrict__ h12) {
  __shared__ float Ss[4096];
  __shared__ float Xs[64 * 32];
  __shared__ float H1[64 * 32];
  int t = threadIdx.x;
  int f0 = blockIdx.x * 32;
#pragma unroll
  for (int i = 0; i < 16; i++) Ss[i * 256 + t] = S[i * 256 + t];
#pragma unroll
  for (int i = 0; i < 8; i++) {
    int idx = i * 256 + t;
    int j = idx >> 5, ff = idx & 31;
    int f = f0 + ff;
    Xs[idx] = (f < 657) ? x[j * 657 + f] : 0.f;
  }
  __syncthreads();
  int ff = t & 31, jg = t >> 5;  // 8 row-groups of 8
  int f = f0 + ff;
  float h1v[8];
#pragma unroll
  for (int jj = 0; jj < 8; jj++) h1v[jj] = 0.f;
  for (int j2 = 0; j2 < 64; j2++) {
    float xv = Xs[j2 * 32 + ff];
#pragma unroll
    for (int jj = 0; jj < 8; jj++) h1v[jj] += Ss[(jg * 8 + jj) * 64 + j2] * xv;
  }
#pragma unroll
  for (int jj = 0; jj < 8; jj++) {
    int j = jg * 8 + jj;
    H1[j * 32 + ff] = h1v[jj];
    if (f < 672) h12[j * 1344 + f] = f2bf_bits(f < 657 ? h1v[jj] : 0.f);
  }
  __syncthreads();
  float h2v[8];
#pragma unroll
  for (int jj = 0; jj < 8; jj++) h2v[jj] = 0.f;
  for (int j2 = 0; j2 < 64; j2++) {
    float xv = H1[j2 * 32 + ff];
#pragma unroll
    for (int jj = 0; jj < 8; jj++) h2v[jj] += Ss[(jg * 8 + jj) * 64 + j2] * xv;
  }
#pragma unroll
  for (int jj = 0; jj < 8; jj++) {
    int j = jg * 8 + jj;
    if (f < 672) h12[j * 1344 + 672 + f] = f2bf_bits(f < 657 ? 2.f * h2v[jj] : 0.f);
  }
}

// hc(64x672 fp32, pre-zeroed) += h12(64x1344) @ BThc^T ; split-K via blockIdx.y
__global__ __launch_bounds__(256) void k_gemm_hc(
    const unsigned short* __restrict__ A,    // 64 x 1344 bf16
    const unsigned short* __restrict__ Bt,   // 768 x 1344 bf16
    float* __restrict__ hc) {                // 64 x 672 fp32
  __shared__ __align__(16) unsigned short As[64 * 32];
  __shared__ __align__(16) unsigned short Bs[128 * 32];
  const int nBase = blockIdx.x * 128;       // 6 tiles
  const int kc0 = blockIdx.y * 192;         // 7 splits x 6 iters
  const int tid = threadIdx.x;
  const int wave = tid >> 6, lane = tid & 63;
  const int wn = wave * 32;
  const int q = lane >> 4, r = lane & 15;
  f32x4 acc[4][2] = {};
  for (int kt = 0; kt < 6; kt++) {
    int k0 = kc0 + kt * 32;
    {
      int c = tid;
      int row = c >> 2, kg = (c & 3) * 8;
      gl2lds16(A + (size_t)row * 1344 + k0 + kg, &As[c * 8]);
    }
#pragma unroll
    for (int i = 0; i < 2; i++) {
      int c = i * 256 + tid;
      int row = c >> 2, kg = (c & 3) * 8;
      gl2lds16(Bt + (size_t)(nBase + row) * 1344 + k0 + kg, &Bs[c * 8]);
    }
    __syncthreads();
    bf16x8 a[4], b[2];
#pragma unroll
    for (int mi = 0; mi < 4; mi++)
      a[mi] = *(const bf16x8*)&As[(mi * 16 + r) * 32 + q * 8];
#pragma unroll
    for (int ni = 0; ni < 2; ni++)
      b[ni] = *(const bf16x8*)&Bs[(wn + ni * 16 + r) * 32 + q * 8];
#pragma unroll
    for (int mi = 0; mi < 4; mi++)
#pragma unroll
      for (int ni = 0; ni < 2; ni++)
        acc[mi][ni] = __builtin_amdgcn_mfma_f32_16x16x32_bf16(a[mi], b[ni], acc[mi][ni], 0, 0, 0);
    __syncthreads();
  }
#pragma unroll
  for (int ni = 0; ni < 2; ni++) {
    int f = nBase + wn + ni * 16 + r;
    if (f >= 672) continue;
#pragma unroll
    for (int mi = 0; mi < 4; mi++)
#pragma unroll
      for (int p = 0; p < 4; p++) {
        int row = mi * 16 + q * 4 + p;
        atomicAdd(&hc[row * 672 + f], acc[mi][ni][p]);
      }
  }
}

// merged prep: pad (blocks 0..21503), wdt (21504..21635), bhc (21636..21887)
__global__ __launch_bounds__(256) void k_prep(const float* __restrict__ x,
                                              const float* __restrict__ cheb_w,
                                              unsigned int* __restrict__ xp,
                                              unsigned short* __restrict__ wt,
                                              unsigned short* __restrict__ bt) {
  __shared__ float tile[64][65];
  int bid = blockIdx.x;
  int t = threadIdx.x;
  if (bid < 21504) {
    int idx = bid * 256 + t;
    int rr = idx / 336, u = idx - rr * 336;
    int c0 = u * 2;
    float a = (c0 < 657) ? x[rr * 657 + c0] : 0.f;
    float b = (c0 + 1 < 657) ? x[rr * 657 + c0 + 1] : 0.f;
    xp[idx] = ((unsigned int)f2bf_bits(b) << 16) | (unsigned int)f2bf_bits(a);
    return;
  }
  const float* W2 = cheb_w + 2 * 657 * 657;
  if (bid < 21636) {
    int rel = bid - 21504;
    int k0 = (rel % 11) * 64, n0 = (rel / 11) * 64;
#pragma unroll
    for (int i = 0; i < 16; i++) {
      int idx = i * 256 + t;
      int kk = idx >> 6, nn = idx & 63;
      int k = k0 + kk, n = n0 + nn;
      float v = 0.f;
      if (k < 657 && n < 657) v = cheb_w[k * 657 + n] - W2[k * 657 + n];
      tile[kk][nn] = v;
    }
    __syncthreads();
#pragma unroll
    for (int i = 0; i < 16; i++) {
      int idx = i * 256 + t;
      int nn = idx >> 6, kk = idx & 63;
      int k = k0 + kk, n = n0 + nn;
      if (k < 672 && n < 768) wt[n * 672 + k] = f2bf_bits(tile[kk][nn]);
    }
    return;
  }
  {
    int rel = bid - 21636;
    int k0 = (rel % 21) * 64, n0 = (rel / 21) * 64;
    const float* W1 = cheb_w + 657 * 657;
#pragma unroll
    for (int i = 0; i < 16; i++) {
      int idx = i * 256 + t;
      int kk = idx >> 6, nn = idx & 63;
      int gk = k0 + kk, n = n0 + nn;
      float v = 0.f;
      if (n < 657) {
        if (gk < 672) {
          if (gk < 657) v = W1[gk * 657 + n];
        } else {
          int k2 = gk - 672;
          if (k2 < 657) v = W2[k2 * 657 + n];
        }
      }
      tile[kk][nn] = v;
    }
    __syncthreads();
#pragma unroll
    for (int i = 0; i < 16; i++) {
      int idx = i * 256 + t;
      int nn = idx >> 6, kk = idx & 63;
      int gk = k0 + kk, n = n0 + nn;
      bt[(size_t)n * 1344 + gk] = f2bf_bits(tile[kk][nn]);
    }
  }
}

// Wt_pad[o][n*672+f] = fc1_w[n*657+f][o] (f<657), else 0.  256 x 43008 bf16.
__global__ __launch_bounds__(256) void k_wt1(const float* __restrict__ W,
                                             unsigned short* __restrict__ Wt) {
  __shared__ float tile[64][65];
  int k0 = blockIdx.x * 64;
  int n0 = blockIdx.y * 64;
  int t = threadIdx.x;
#pragma unroll
  for (int i = 0; i < 16; i++) {
    int idx = i * 256 + t;
    int kk = idx >> 6, nn = idx & 63;
    int kg = k0 + kk;
    int nnode = kg / 672, f = kg - nnode * 672;
    float v = 0.f;
    if (f < 657) v = W[(size_t)(nnode * 657 + f) * 256 + n0 + nn];
    tile[kk][nn] = v;
  }
  __syncthreads();
#pragma unroll
  for (int i = 0; i < 16; i++) {
    int idx = i * 256 + t;
    int nn = idx >> 6, kk = idx & 63;
    Wt[(size_t)(n0 + nn) * 43008 + k0 + kk] = f2bf_bits(tile[kk][nn]);
  }
}

// ---------------- main GEMM: out1 = bn1(softplus(xf@Wd + cheb_b [+ hc rows<64])) ----------------
// 64x128 tile, BK=64 (+32 tail), XOR-swizzled LDS (conflict-free ds_read_b128),
// fast-softplus + folded-BN epilogue, LDS-bounce 16B stores.
__global__ __launch_bounds__(256) void k_gemm_main(
    const unsigned short* __restrict__ Ap,   // 16384 x 672 bf16
    const unsigned short* __restrict__ BT,   // 768 x 672 bf16
    const float* __restrict__ hc,            // 64 x 672
    const float* __restrict__ cheb_b,
    const float* __restrict__ bn1,           // 4 x 657
    unsigned short* __restrict__ out1) {     // 16384 x 672 bf16 (padded)
  __shared__ __align__(16) unsigned short lds[12288];  // 24 KB
  unsigned short* As = lds;            // 64 rows x 64 k (swizzled chunks)
  unsigned short* Bs = lds + 4096;     // 128 rows x 64 k
  const int mBase = blockIdx.x * 64;
  const int nBase = blockIdx.y * 128;
  const int tid = threadIdx.x;
  const int wave = tid >> 6, lane = tid & 63;
  const int wm = (wave & 1) * 32;      // 2x2 wave grid: each wave 32x64
  const int wn = (wave >> 1) * 64;
  const int q = lane >> 4, r = lane & 15;
  f32x4 acc[2][4] = {};
  // 10 full BK=64 tiles. LDS slot kc of row holds global chunk kc^(row&7):
  // the staging lane fetches chunk (kc^(row&7)); reads recover chunk g at slot g^(row&7).
  for (int k0 = 0; k0 < 640; k0 += 64) {
#pragma unroll
    for (int i = 0; i < 2; i++) {
      int c = i * 256 + tid;             // 512 A-chunks: row=c>>3, kc=c&7
      int row = c >> 3, kc = c & 7;
      gl2lds16(Ap + (size_t)(mBase + row) * 672 + k0 + (kc ^ (row & 7)) * 8, &As[c * 8]);
    }
#pragma unroll
    for (int i = 0; i < 4; i++) {
      int c = i * 256 + tid;             // 1024 B-chunks
      int row = c >> 3, kc = c & 7;
      gl2lds16(BT + (size_t)(nBase + row) * 672 + k0 + (kc ^ (row & 7)) * 8, &Bs[c * 8]);
    }
    __syncthreads();
#pragma unroll
    for (int kk = 0; kk < 2; kk++) {
      bf16x8 a[2], b[4];
#pragma unroll
      for (int mi = 0; mi < 2; mi++) {
        int ar = wm + mi * 16 + r;
        a[mi] = *(const bf16x8*)&As[ar * 64 + ((kk * 4 + q) ^ (ar & 7)) * 8];
      }
#pragma unroll
      for (int ni = 0; ni < 4; ni++) {
        int br = wn + ni * 16 + r;
        b[ni] = *(const bf16x8*)&Bs[br * 64 + ((kk * 4 + q) ^ (br & 7)) * 8];
      }
#pragma unroll
      for (int mi = 0; mi < 2; mi++)
#pragma unroll
        for (int ni = 0; ni < 4; ni++)
          acc[mi][ni] = __builtin_amdgcn_mfma_f32_16x16x32_bf16(a[mi], b[ni], acc[mi][ni], 0, 0, 0);
    }
    __syncthreads();
  }
  // K tail: 32 wide at k0=640, packed stride 32, swizzle mask 3
  {
    {
      int row = tid >> 2, kc = tid & 3;  // 256 A-chunks
      gl2lds16(Ap + (size_t)(mBase + row) * 672 + 640 + ((kc ^ (row & 3)) * 8), &As[tid * 8]);
    }
#pragma unroll
    for (int i = 0; i < 2; i++) {
      int c = i * 256 + tid;             // 512 B-chunks
      int row = c >> 2, kc = c & 3;
      gl2lds16(BT + (size_t)(nBase + row) * 672 + 640 + ((kc ^ (row & 3)) * 8), &Bs[c * 8]);
    }
    __syncthreads();
    bf16x8 a[2], b[4];
#pragma unroll
    for (int mi = 0; mi < 2; mi++) {
      int ar = wm + mi * 16 + r;
      a[mi] = *(const bf16x8*)&As[ar * 32 + ((q ^ (ar & 3)) * 8)];
    }
#pragma unroll
    for (int ni = 0; ni < 4; ni++) {
      int br = wn + ni * 16 + r;
      b[ni] = *(const bf16x8*)&Bs[br * 32 + ((q ^ (br & 3)) * 8)];
    }
#pragma unroll
    for (int mi = 0; mi < 2; mi++)
#pragma unroll
      for (int ni = 0; ni < 4; ni++)
        acc[mi][ni] = __builtin_amdgcn_mfma_f32_16x16x32_bf16(a[mi], b[ni], acc[mi][ni], 0, 0, 0);
    __syncthreads();
  }
  // epilogue: fast softplus + folded BN in regs -> per-wave LDS bounce -> 16B stores
  const bool add_hc = (mBase == 0);
  unsigned short* sh = lds + wave * 2048;  // 32x64 per wave (4 KB)
#pragma unroll
  for (int ni = 0; ni < 4; ni++) {
    int f = nBase + wn + ni * 16 + r;
    int fc = f < 657 ? f : 656;
    float cb = cheb_b[fc];
    float g1 = bn1[fc], b1 = bn1[657 + fc];
    float m1 = bn1[2 * 657 + fc], v1 = bn1[3 * 657 + fc];
    float Asc = g1 * __frsqrt_rn(v1 + EPSF);
    float Bsh = b1 - m1 * Asc;
#pragma unroll
    for (int mi = 0; mi < 2; mi++) {
#pragma unroll
      for (int p = 0; p < 4; p++) {
        int lrow = mi * 16 + q * 4 + p;
        float v = acc[mi][ni][p] + cb;
        if (add_hc && f < 672) v += hc[(wm + lrow) * 672 + f];
        v = softplus_fast(v) * Asc + Bsh;
        if (f >= 657) v = 0.f;
        sh[lrow * 64 + ni * 16 + r] = f2bf_bits(v);
      }
    }
  }
  // each wave reads only its own bounce region; compiler inserts lgkm waits
#pragma unroll
  for (int j = 0; j < 4; j++) {
    int c = j * 64 + lane;               // 256 chunks of 16B per wave
    int lrow = c >> 3, seg = c & 7;
    int col = nBase + wn + seg * 8;
    if (col < 672) {
      uint4 v = *(const uint4*)&sh[lrow * 64 + seg * 8];
      *(uint4*)&out1[(size_t)(mBase + wm + lrow) * 672 + col] = v;
    }
  }
}

// ---------------- fc1 GEMM split-K: Cacc += out1(256x43008) @ Wt_pad^T ----------------
__global__ __launch_bounds__(256) void k_gemm_fc1(
    const unsigned short* __restrict__ A,    // 256 x 43008 bf16
    const unsigned short* __restrict__ Bt,   // 256 x 43008 bf16 (Wt_pad)
    float* __restrict__ Cacc) {              // 256 x 256, pre-zeroed
  __shared__ __align__(16) unsigned short As[128 * 32];
  __shared__ __align__(16) unsigned short Bs[128 * 32];
  const int mBase = blockIdx.x * 128;
  const int nBase = blockIdx.y * 128;
  const int kc0 = blockIdx.z * 512;  // 84 * 512 = 43008
  const int tid = threadIdx.x;
  const int wave = tid >> 6, lane = tid & 63;
  const int wm = (wave >> 1) * 64, wn = (wave & 1) * 64;
  const int q = lane >> 4, r = lane & 15;
  f32x4 acc[4][4] = {};
  for (int kt = 0; kt < 16; kt++) {
    int k0 = kc0 + kt * 32;
#pragma unroll
    for (int i = 0; i < 2; i++) {
      int c = i * 256 + tid;
      int row = c >> 2, kg = (c & 3) * 8;
      gl2lds16(A + (size_t)(mBase + row) * 43008 + k0 + kg, &As[c * 8]);
      gl2lds16(Bt + (size_t)(nBase + row) * 43008 + k0 + kg, &Bs[c * 8]);
    }
    __syncthreads();
    bf16x8 a[4], b[4];
#pragma unroll
    for (int mi = 0; mi < 4; mi++)
      a[mi] = *(const bf16x8*)&As[(wm + mi * 16 + r) * 32 + q * 8];
#pragma unroll
    for (int ni = 0; ni < 4; ni++)
      b[ni] = *(const bf16x8*)&Bs[(wn + ni * 16 + r) * 32 + q * 8];
#pragma unroll
    for (int mi = 0; mi < 4; mi++)
#pragma unroll
      for (int ni = 0; ni < 4; ni++)
        acc[mi][ni] = __builtin_amdgcn_mfma_f32_16x16x32_bf16(a[mi], b[ni], acc[mi][ni], 0, 0, 0);
    __syncthreads();
  }
#pragma unroll
  for (int ni = 0; ni < 4; ni++) {
    int col = nBase + wn + ni * 16 + r;
#pragma unroll
    for (int mi = 0; mi < 4; mi++)
#pragma unroll
      for (int p = 0; p < 4; p++) {
        int row = mBase + wm + mi * 16 + q * 4 + p;
        atomicAdd(&Cacc[row * 256 + col], acc[mi][ni][p]);
      }
  }
}

// ---------------- tail ----------------
__global__ __launch_bounds__(256) void k_final(
    const float* __restrict__ Cacc,
    const float* __restrict__ fc1_b,
    const float* __restrict__ bnf1,
    const float* __restrict__ fc2_w,
    const float* __restrict__ fc2_b,
    const float* __restrict__ bnf2,
    const float* __restrict__ fc3_w,
    const float* __restrict__ fc3_b,
    const float* __restrict__ bnf3,
    float* __restrict__ out) {
  __shared__ float a1[256];
  __shared__ float a2[32];
  __shared__ float z[4];
  int b = blockIdx.x, t = threadIdx.x;
  {
    float v = Cacc[b * 256 + t] + fc1_b[t];
    v = softplus_f(v);
    float g = bnf1[t], bb = bnf1[256 + t];
    float m = bnf1[512 + t], vv = bnf1[768 + t];
    a1[t] = g * (v - m) / sqrtf(vv + EPSF) + bb;
  }
  __syncthreads();
  if (t < 32) {
    float s = fc2_b[t];
#pragma unroll 8
    for (int k = 0; k < 256; k++) s += a1[k] * fc2_w[k * 32 + t];
    s = softplus_f(s);
    float g = bnf2[t], bb = bnf2[32 + t];
    float m = bnf2[64 + t], vv = bnf2[96 + t];
    a2[t] = g * (s - m) / sqrtf(vv + EPSF) + bb;
  }
  __syncthreads();
  if (t < 4) {
    float s = fc3_b[t];
#pragma unroll
    for (int k = 0; k < 32; k++) s += a2[k] * fc3_w[k * 4 + t];
    float g = bnf3[t], bb = bnf3[4 + t];
    float m = bnf3[8 + t], vv = bnf3[12 + t];
    s = g * (s - m) / sqrtf(vv + EPSF) + bb;  // bn BEFORE softplus here
    z[t] = softplus_f(s);
  }
  __syncthreads();
  if (t == 0) {
    float mx = fmaxf(fmaxf(z[0], z[1]), fmaxf(z[2], z[3]));
    float e0 = expf(z[0] - mx), e1 = expf(z[1] - mx);
    float e2 = expf(z[2] - mx), e3 = expf(z[3] - mx);
    float inv = 1.0f / (e0 + e1 + e2 + e3);
    out[b * 4 + 0] = e0 * inv;
    out[b * 4 + 1] = e1 * inv;
    out[b * 4 + 2] = e2 * inv;
    out[b * 4 + 3] = e3 * inv;
  }
}

extern "C" void kernel_launch(void* const* d_in, const int* in_sizes, int n_in,
                              void* d_out, int out_size, void* d_ws, size_t ws_size,
                              hipStream_t stream) {
  const float* x      = (const float*)d_in[0];
  const float* adj    = (const float*)d_in[1];
  const int*   eidx   = (const int*)d_in[2];
  const float* cheb_w = (const float*)d_in[3];
  const float* cheb_b = (const float*)d_in[4];
  const float* fc1_w  = (const float*)d_in[5];
  const float* fc1_b  = (const float*)d_in[6];
  const float* fc2_w  = (const float*)d_in[7];
  const float* fc2_b  = (const float*)d_in[8];
  const float* fc3_w  = (const float*)d_in[9];
  const float* fc3_b  = (const float*)d_in[10];
  const float* bn1    = (const float*)d_in[11];
  const float* bnf1   = (const float*)d_in[12];
  const float* bnf2   = (const float*)d_in[13];
  const float* bnf3   = (const float*)d_in[14];

  char* ws = (char*)d_ws;
  float* S       = (float*)(ws + 0);          // 16384 B
  float* wsum    = (float*)(ws + 16384);      // 2048 B (memset region start)
  float* hc      = (float*)(ws + 18432);      // 172032 B (64 x 672 fp32)
  float* fc1_acc = (float*)(ws + 190464);     // 262144 B (memset region end)
  unsigned short* h12  = (unsigned short*)(ws + 452608);      // 172032 B
  unsigned short* xpad = (unsigned short*)(ws + 624640);      // 22020096 B
  unsigned short* wdt  = (unsigned short*)(ws + 22644736);    // 1032192 B
  unsigned short* out1 = (unsigned short*)(ws + 23676928);    // 22020096 B (end ~45.7 MB)
  // BThc aliases out1 (consumed by k_gemm_hc before k_gemm_main writes out1).
  unsigned short* BThc = out1;
  // Wt aliases xpad (written by k_wt1 after k_gemm_main consumed xpad).
  unsigned short* Wt = xpad;

  (void)hipMemsetAsync(ws + 16384, 0, 436224, stream);  // wsum + hc + fc1_acc

  k_prep<<<21888, 256, 0, stream>>>(x, cheb_w, (unsigned int*)xpad, wdt, BThc);
  k_wsum<<<64, 256, 0, stream>>>(adj, eidx, wsum);
  k_S<<<1, 512, 0, stream>>>(eidx, wsum, S);
  k_h12f<<<21, 256, 0, stream>>>(S, x, h12);
  k_gemm_hc<<<dim3(6, 7), 256, 0, stream>>>(h12, BThc, hc);
  k_gemm_main<<<dim3(256, 6), 256, 0, stream>>>(xpad, wdt, hc, cheb_b, bn1, out1);
  k_wt1<<<dim3(672, 4), 256, 0, stream>>>(fc1_w, Wt);
  k_gemm_fc1<<<dim3(2, 2, 84), 256, 0, stream>>>(out1, Wt, fc1_acc);
  k_final<<<256, 256, 0, stream>>>(fc1_acc, fc1_b, bnf1, fc2_w, fc2_b, bnf2,
                                   fc3_w, fc3_b, bnf3, (float*)d_out);
}

// Round 9
// 261.556 us; speedup vs baseline: 1.3020x; 1.0938x over previous
//
#include <hip/hip_runtime.h>
#include <hip/hip_bf16.h>

#define EPSF 1e-5f

typedef __bf16 bf16x8 __attribute__((ext_vector_type(8)));
typedef float f32x4 __attribute__((ext_vector_type(4)));

__device__ __forceinline__ float softplus_f(float x) {
  return fmaxf(x, 0.0f) + log1pf(expf(-fabsf(x)));
}

__device__ __forceinline__ float softplus_fast(float x) {
  return fmaxf(x, 0.0f) + __logf(1.0f + __expf(-fabsf(x)));
}

__device__ __forceinline__ unsigned short f2bf_bits(float f) {
  union { float f; unsigned int u; } v; v.f = f;
  unsigned int u = v.u;
  unsigned int lsb = (u >> 16) & 1u;
  u += 0x7fffu + lsb;  // round-to-nearest-even
  return (unsigned short)(u >> 16);
}

__device__ __forceinline__ void gl2lds16(const void* g, void* l) {
  __builtin_amdgcn_global_load_lds((const __attribute__((address_space(1))) void*)g,
                                   (__attribute__((address_space(3))) void*)l,
                                   16, 0, 0);
}

// ---------------- graph prep ----------------
__global__ __launch_bounds__(256) void k_wsum(const float* __restrict__ adj,
                                              const int* __restrict__ eidx,
                                              float* __restrict__ wsum) {  // pre-zeroed
  __shared__ float A[4096];
  int g = blockIdx.x, t = threadIdx.x;
  int s0 = eidx[t], d0 = eidx[512 + t];
  int s1 = eidx[256 + t], d1 = eidx[768 + t];
  float acc0 = 0.f, acc1 = 0.f;
  for (int bb = 0; bb < 4; bb++) {
    const float* ab = adj + (size_t)(g * 4 + bb) * 4096;
#pragma unroll
    for (int i = 0; i < 16; i++) A[i * 256 + t] = ab[i * 256 + t];
    __syncthreads();
    acc0 += fmaxf(A[s0 * 64 + d0], A[d0 * 64 + s0]);
    acc1 += fmaxf(A[s1 * 64 + d1], A[d1 * 64 + s1]);
    __syncthreads();
  }
  atomicAdd(&wsum[t], acc0);
  atomicAdd(&wsum[256 + t], acc1);
}

__global__ __launch_bounds__(512) void k_S(const int* __restrict__ eidx,
                                           const float* __restrict__ wsum,
                                           float* __restrict__ S) {
  __shared__ float deg[64];
  __shared__ float Ssh[4096];
  int t = threadIdx.x;
  if (t < 64) deg[t] = 0.f;
  for (int i = t; i < 4096; i += 512) Ssh[i] = 0.f;
  __syncthreads();
  int s = eidx[t], d = eidx[512 + t];
  float w = wsum[t];
  atomicAdd(&deg[s], w);
  __syncthreads();
  float ds = deg[s], dd = deg[d];
  float dis = ds > 0.f ? 1.0f / sqrtf(ds) : 0.f;
  float did = dd > 0.f ? 1.0f / sqrtf(dd) : 0.f;
  float coef = -dis * w * did;
  atomicAdd(&Ssh[d * 64 + s], coef);
  __syncthreads();
  for (int i = t; i < 4096; i += 512) S[i] = Ssh[i];
}

// fused h1 = S@x, h2 = 2*S@h1, packed into h12[64][1344] bf16 = [h1|pad|h2|pad]
__global__ __launch_bounds__(256) void k_h12f(const float* __restrict__ S,
                                              const float* __restrict__ x,
                                              unsigned short* __restrict__ h12) {
  __shared__ float Ss[4096];
  __shared__ float Xs[64 * 32];
  __shared__ float H1[64 * 32];
  int t = threadIdx.x;
  int f0 = blockIdx.x * 32;
#pragma unroll
  for (int i = 0; i < 16; i++) Ss[i * 256 + t] = S[i * 256 + t];
#pragma unroll
  for (int i = 0; i < 8; i++) {
    int idx = i * 256 + t;
    int j = idx >> 5, ff = idx & 31;
    int f = f0 + ff;
    Xs[idx] = (f < 657) ? x[j * 657 + f] : 0.f;
  }
  __syncthreads();
  int ff = t & 31, jg = t >> 5;
  int f = f0 + ff;
  float h1v[8];
#pragma unroll
  for (int jj = 0; jj < 8; jj++) h1v[jj] = 0.f;
  for (int j2 = 0; j2 < 64; j2++) {
    float xv = Xs[j2 * 32 + ff];
#pragma unroll
    for (int jj = 0; jj < 8; jj++) h1v[jj] += Ss[(jg * 8 + jj) * 64 + j2] * xv;
  }
#pragma unroll
  for (int jj = 0; jj < 8; jj++) {
    int j = jg * 8 + jj;
    H1[j * 32 + ff] = h1v[jj];
    if (f < 672) h12[j * 1344 + f] = f2bf_bits(f < 657 ? h1v[jj] : 0.f);
  }
  __syncthreads();
  float h2v[8];
#pragma unroll
  for (int jj = 0; jj < 8; jj++) h2v[jj] = 0.f;
  for (int j2 = 0; j2 < 64; j2++) {
    float xv = H1[j2 * 32 + ff];
#pragma unroll
    for (int jj = 0; jj < 8; jj++) h2v[jj] += Ss[(jg * 8 + jj) * 64 + j2] * xv;
  }
#pragma unroll
  for (int jj = 0; jj < 8; jj++) {
    int j = jg * 8 + jj;
    if (f < 672) h12[j * 1344 + 672 + f] = f2bf_bits(f < 657 ? 2.f * h2v[jj] : 0.f);
  }
}

// hc(64x672 fp32, pre-zeroed) += h12(64x1344) @ BThc^T ; split-K via blockIdx.y
__global__ __launch_bounds__(256) void k_gemm_hc(
    const unsigned short* __restrict__ A,    // 64 x 1344 bf16
    const unsigned short* __restrict__ Bt,   // 768 x 1344 bf16
    float* __restrict__ hc) {                // 64 x 672 fp32
  __shared__ __align__(16) unsigned short As[64 * 32];
  __shared__ __align__(16) unsigned short Bs[128 * 32];
  const int nBase = blockIdx.x * 128;
  const int kc0 = blockIdx.y * 192;
  const int tid = threadIdx.x;
  const int wave = tid >> 6, lane = tid & 63;
  const int wn = wave * 32;
  const int q = lane >> 4, r = lane & 15;
  f32x4 acc[4][2] = {};
  for (int kt = 0; kt < 6; kt++) {
    int k0 = kc0 + kt * 32;
    {
      int c = tid;
      int row = c >> 2, kg = (c & 3) * 8;
      gl2lds16(A + (size_t)row * 1344 + k0 + kg, &As[c * 8]);
    }
#pragma unroll
    for (int i = 0; i < 2; i++) {
      int c = i * 256 + tid;
      int row = c >> 2, kg = (c & 3) * 8;
      gl2lds16(Bt + (size_t)(nBase + row) * 1344 + k0 + kg, &Bs[c * 8]);
    }
    __syncthreads();
    bf16x8 a[4], b[2];
#pragma unroll
    for (int mi = 0; mi < 4; mi++)
      a[mi] = *(const bf16x8*)&As[(mi * 16 + r) * 32 + q * 8];
#pragma unroll
    for (int ni = 0; ni < 2; ni++)
      b[ni] = *(const bf16x8*)&Bs[(wn + ni * 16 + r) * 32 + q * 8];
#pragma unroll
    for (int mi = 0; mi < 4; mi++)
#pragma unroll
      for (int ni = 0; ni < 2; ni++)
        acc[mi][ni] = __builtin_amdgcn_mfma_f32_16x16x32_bf16(a[mi], b[ni], acc[mi][ni], 0, 0, 0);
    __syncthreads();
  }
#pragma unroll
  for (int ni = 0; ni < 2; ni++) {
    int f = nBase + wn + ni * 16 + r;
    if (f >= 672) continue;
#pragma unroll
    for (int mi = 0; mi < 4; mi++)
#pragma unroll
      for (int p = 0; p < 4; p++) {
        int row = mi * 16 + q * 4 + p;
        atomicAdd(&hc[row * 672 + f], acc[mi][ni][p]);
      }
  }
}

// merged prep: pad (0..21503), wdt (21504..21635), bhc (21636..21887), wt1 (21888..24575)
__global__ __launch_bounds__(256) void k_prep(const float* __restrict__ x,
                                              const float* __restrict__ cheb_w,
                                              const float* __restrict__ fc1_w,
                                              unsigned int* __restrict__ xp,
                                              unsigned short* __restrict__ wt,
                                              unsigned short* __restrict__ bt,
                                              unsigned short* __restrict__ Wt) {
  __shared__ float tile[64][65];
  int bid = blockIdx.x;
  int t = threadIdx.x;
  if (bid < 21504) {
    int idx = bid * 256 + t;
    int rr = idx / 336, u = idx - rr * 336;
    int c0 = u * 2;
    float a = (c0 < 657) ? x[rr * 657 + c0] : 0.f;
    float b = (c0 + 1 < 657) ? x[rr * 657 + c0 + 1] : 0.f;
    xp[idx] = ((unsigned int)f2bf_bits(b) << 16) | (unsigned int)f2bf_bits(a);
    return;
  }
  const float* W2 = cheb_w + 2 * 657 * 657;
  if (bid < 21636) {
    int rel = bid - 21504;
    int k0 = (rel % 11) * 64, n0 = (rel / 11) * 64;
#pragma unroll
    for (int i = 0; i < 16; i++) {
      int idx = i * 256 + t;
      int kk = idx >> 6, nn = idx & 63;
      int k = k0 + kk, n = n0 + nn;
      float v = 0.f;
      if (k < 657 && n < 657) v = cheb_w[k * 657 + n] - W2[k * 657 + n];
      tile[kk][nn] = v;
    }
    __syncthreads();
#pragma unroll
    for (int i = 0; i < 16; i++) {
      int idx = i * 256 + t;
      int nn = idx >> 6, kk = idx & 63;
      int k = k0 + kk, n = n0 + nn;
      if (k < 672 && n < 768) wt[n * 672 + k] = f2bf_bits(tile[kk][nn]);
    }
    return;
  }
  if (bid < 21888) {
    int rel = bid - 21636;
    int k0 = (rel % 21) * 64, n0 = (rel / 21) * 64;
    const float* W1 = cheb_w + 657 * 657;
#pragma unroll
    for (int i = 0; i < 16; i++) {
      int idx = i * 256 + t;
      int kk = idx >> 6, nn = idx & 63;
      int gk = k0 + kk, n = n0 + nn;
      float v = 0.f;
      if (n < 657) {
        if (gk < 672) {
          if (gk < 657) v = W1[gk * 657 + n];
        } else {
          int k2 = gk - 672;
          if (k2 < 657) v = W2[k2 * 657 + n];
        }
      }
      tile[kk][nn] = v;
    }
    __syncthreads();
#pragma unroll
    for (int i = 0; i < 16; i++) {
      int idx = i * 256 + t;
      int nn = idx >> 6, kk = idx & 63;
      int gk = k0 + kk, n = n0 + nn;
      bt[(size_t)n * 1344 + gk] = f2bf_bits(tile[kk][nn]);
    }
    return;
  }
  {
    // Wt_pad[o][n*672+f] = fc1_w[n*657+f][o] (f<657), else 0.  256 x 43008 bf16.
    int rel = bid - 21888;                 // 2688 = 672 x 4
    int k0 = (rel % 672) * 64, n0 = (rel / 672) * 64;
#pragma unroll
    for (int i = 0; i < 16; i++) {
      int idx = i * 256 + t;
      int kk = idx >> 6, nn = idx & 63;
      int kg = k0 + kk;
      int nnode = kg / 672, f = kg - nnode * 672;
      float v = 0.f;
      if (f < 657) v = fc1_w[(size_t)(nnode * 657 + f) * 256 + n0 + nn];
      tile[kk][nn] = v;
    }
    __syncthreads();
#pragma unroll
    for (int i = 0; i < 16; i++) {
      int idx = i * 256 + t;
      int nn = idx >> 6, kk = idx & 63;
      Wt[(size_t)(n0 + nn) * 43008 + k0 + kk] = f2bf_bits(tile[kk][nn]);
    }
  }
}

// ---------------- main GEMM (proven R8 config) ----------------
__global__ __launch_bounds__(256) void k_gemm_main(
    const unsigned short* __restrict__ Ap,   // 16384 x 672 bf16
    const unsigned short* __restrict__ BT,   // 768 x 672 bf16
    const float* __restrict__ hc,            // 64 x 672
    const float* __restrict__ cheb_b,
    const float* __restrict__ bn1,           // 4 x 657
    unsigned short* __restrict__ out1) {     // 16384 x 672 bf16 (padded)
  __shared__ __align__(16) unsigned short lds[12288];  // 24 KB
  unsigned short* As = lds;            // 64 rows x 64 k (swizzled chunks)
  unsigned short* Bs = lds + 4096;     // 128 rows x 64 k
  const int mBase = blockIdx.x * 64;
  const int nBase = blockIdx.y * 128;
  const int tid = threadIdx.x;
  const int wave = tid >> 6, lane = tid & 63;
  const int wm = (wave & 1) * 32;
  const int wn = (wave >> 1) * 64;
  const int q = lane >> 4, r = lane & 15;
  f32x4 acc[2][4] = {};
  for (int k0 = 0; k0 < 640; k0 += 64) {
#pragma unroll
    for (int i = 0; i < 2; i++) {
      int c = i * 256 + tid;
      int row = c >> 3, kc = c & 7;
      gl2lds16(Ap + (size_t)(mBase + row) * 672 + k0 + (kc ^ (row & 7)) * 8, &As[c * 8]);
    }
#pragma unroll
    for (int i = 0; i < 4; i++) {
      int c = i * 256 + tid;
      int row = c >> 3, kc = c & 7;
      gl2lds16(BT + (size_t)(nBase + row) * 672 + k0 + (kc ^ (row & 7)) * 8, &Bs[c * 8]);
    }
    __syncthreads();
#pragma unroll
    for (int kk = 0; kk < 2; kk++) {
      bf16x8 a[2], b[4];
#pragma unroll
      for (int mi = 0; mi < 2; mi++) {
        int ar = wm + mi * 16 + r;
        a[mi] = *(const bf16x8*)&As[ar * 64 + ((kk * 4 + q) ^ (ar & 7)) * 8];
      }
#pragma unroll
      for (int ni = 0; ni < 4; ni++) {
        int br = wn + ni * 16 + r;
        b[ni] = *(const bf16x8*)&Bs[br * 64 + ((kk * 4 + q) ^ (br & 7)) * 8];
      }
#pragma unroll
      for (int mi = 0; mi < 2; mi++)
#pragma unroll
        for (int ni = 0; ni < 4; ni++)
          acc[mi][ni] = __builtin_amdgcn_mfma_f32_16x16x32_bf16(a[mi], b[ni], acc[mi][ni], 0, 0, 0);
    }
    __syncthreads();
  }
  // K tail: 32 wide at k0=640
  {
    {
      int row = tid >> 2, kc = tid & 3;
      gl2lds16(Ap + (size_t)(mBase + row) * 672 + 640 + ((kc ^ (row & 3)) * 8), &As[tid * 8]);
    }
#pragma unroll
    for (int i = 0; i < 2; i++) {
      int c = i * 256 + tid;
      int row = c >> 2, kc = c & 3;
      gl2lds16(BT + (size_t)(nBase + row) * 672 + 640 + ((kc ^ (row & 3)) * 8), &Bs[c * 8]);
    }
    __syncthreads();
    bf16x8 a[2], b[4];
#pragma unroll
    for (int mi = 0; mi < 2; mi++) {
      int ar = wm + mi * 16 + r;
      a[mi] = *(const bf16x8*)&As[ar * 32 + ((q ^ (ar & 3)) * 8)];
    }
#pragma unroll
    for (int ni = 0; ni < 4; ni++) {
      int br = wn + ni * 16 + r;
      b[ni] = *(const bf16x8*)&Bs[br * 32 + ((q ^ (br & 3)) * 8)];
    }
#pragma unroll
    for (int mi = 0; mi < 2; mi++)
#pragma unroll
      for (int ni = 0; ni < 4; ni++)
        acc[mi][ni] = __builtin_amdgcn_mfma_f32_16x16x32_bf16(a[mi], b[ni], acc[mi][ni], 0, 0, 0);
    __syncthreads();
  }
  const bool add_hc = (mBase == 0);
  unsigned short* sh = lds + wave * 2048;
#pragma unroll
  for (int ni = 0; ni < 4; ni++) {
    int f = nBase + wn + ni * 16 + r;
    int fc = f < 657 ? f : 656;
    float cb = cheb_b[fc];
    float g1 = bn1[fc], b1 = bn1[657 + fc];
    float m1 = bn1[2 * 657 + fc], v1 = bn1[3 * 657 + fc];
    float Asc = g1 * __frsqrt_rn(v1 + EPSF);
    float Bsh = b1 - m1 * Asc;
#pragma unroll
    for (int mi = 0; mi < 2; mi++) {
#pragma unroll
      for (int p = 0; p < 4; p++) {
        int lrow = mi * 16 + q * 4 + p;
        float v = acc[mi][ni][p] + cb;
        if (add_hc && f < 672) v += hc[(wm + lrow) * 672 + f];
        v = softplus_fast(v) * Asc + Bsh;
        if (f >= 657) v = 0.f;
        sh[lrow * 64 + ni * 16 + r] = f2bf_bits(v);
      }
    }
  }
#pragma unroll
  for (int j = 0; j < 4; j++) {
    int c = j * 64 + lane;
    int lrow = c >> 3, seg = c & 7;
    int col = nBase + wn + seg * 8;
    if (col < 672) {
      uint4 v = *(const uint4*)&sh[lrow * 64 + seg * 8];
      *(uint4*)&out1[(size_t)(mBase + wm + lrow) * 672 + col] = v;
    }
  }
}

// ---------------- fc1 GEMM split-K: partial[z] = tile of out1 @ Wt^T (no atomics) ----------------
__global__ __launch_bounds__(256) void k_gemm_fc1(
    const unsigned short* __restrict__ A,    // 256 x 43008 bf16
    const unsigned short* __restrict__ Bt,   // 256 x 43008 bf16 (Wt_pad)
    float* __restrict__ part) {              // 84 x 256 x 256 fp32
  __shared__ __align__(16) unsigned short As[128 * 32];
  __shared__ __align__(16) unsigned short Bs[128 * 32];
  const int mBase = blockIdx.x * 128;
  const int nBase = blockIdx.y * 128;
  const int kc0 = blockIdx.z * 512;  // 84 * 512 = 43008
  const int tid = threadIdx.x;
  const int wave = tid >> 6, lane = tid & 63;
  const int wm = (wave >> 1) * 64, wn = (wave & 1) * 64;
  const int q = lane >> 4, r = lane & 15;
  f32x4 acc[4][4] = {};
  for (int kt = 0; kt < 16; kt++) {
    int k0 = kc0 + kt * 32;
#pragma unroll
    for (int i = 0; i < 2; i++) {
      int c = i * 256 + tid;
      int row = c >> 2, kg = (c & 3) * 8;
      gl2lds16(A + (size_t)(mBase + row) * 43008 + k0 + kg, &As[c * 8]);
      gl2lds16(Bt + (size_t)(nBase + row) * 43008 + k0 + kg, &Bs[c * 8]);
    }
    __syncthreads();
    bf16x8 a[4], b[4];
#pragma unroll
    for (int mi = 0; mi < 4; mi++)
      a[mi] = *(const bf16x8*)&As[(wm + mi * 16 + r) * 32 + q * 8];
#pragma unroll
    for (int ni = 0; ni < 4; ni++)
      b[ni] = *(const bf16x8*)&Bs[(wn + ni * 16 + r) * 32 + q * 8];
#pragma unroll
    for (int mi = 0; mi < 4; mi++)
#pragma unroll
      for (int ni = 0; ni < 4; ni++)
        acc[mi][ni] = __builtin_amdgcn_mfma_f32_16x16x32_bf16(a[mi], b[ni], acc[mi][ni], 0, 0, 0);
    __syncthreads();
  }
  float* dst = part + (size_t)blockIdx.z * 65536;
#pragma unroll
  for (int ni = 0; ni < 4; ni++) {
    int col = nBase + wn + ni * 16 + r;
#pragma unroll
    for (int mi = 0; mi < 4; mi++)
#pragma unroll
      for (int p = 0; p < 4; p++) {
        int row = mBase + wm + mi * 16 + q * 4 + p;
        dst[row * 256 + col] = acc[mi][ni][p];
      }
  }
}

// ---------------- tail: split-K reduce + bn/softplus + fc2 + fc3 + softmax ----------------
__global__ __launch_bounds__(256) void k_final(
    const float* __restrict__ part,          // 84 x 256 x 256
    const float* __restrict__ fc1_b,
    const float* __restrict__ bnf1,
    const float* __restrict__ fc2_w,
    const float* __restrict__ fc2_b,
    const float* __restrict__ bnf2,
    const float* __restrict__ fc3_w,
    const float* __restrict__ fc3_b,
    const float* __restrict__ bnf3,
    float* __restrict__ out) {
  __shared__ float a1[256];
  __shared__ float a2[32];
  __shared__ float z[4];
  int b = blockIdx.x, t = threadIdx.x;
  {
    const float* p = part + b * 256 + t;
    float s0 = 0.f, s1 = 0.f, s2 = 0.f, s3 = 0.f;
#pragma unroll 4
    for (int zz = 0; zz < 84; zz += 4) {
      s0 += p[(size_t)zz * 65536];
      s1 += p[(size_t)(zz + 1) * 65536];
      s2 += p[(size_t)(zz + 2) * 65536];
      s3 += p[(size_t)(zz + 3) * 65536];
    }
    float v = (s0 + s1) + (s2 + s3) + fc1_b[t];
    v = softplus_f(v);
    float g = bnf1[t], bb = bnf1[256 + t];
    float m = bnf1[512 + t], vv = bnf1[768 + t];
    a1[t] = g * (v - m) / sqrtf(vv + EPSF) + bb;
  }
  __syncthreads();
  if (t < 32) {
    float s = fc2_b[t];
#pragma unroll 8
    for (int k = 0; k < 256; k++) s += a1[k] * fc2_w[k * 32 + t];
    s = softplus_f(s);
    float g = bnf2[t], bb = bnf2[32 + t];
    float m = bnf2[64 + t], vv = bnf2[96 + t];
    a2[t] = g * (s - m) / sqrtf(vv + EPSF) + bb;
  }
  __syncthreads();
  if (t < 4) {
    float s = fc3_b[t];
#pragma unroll
    for (int k = 0; k < 32; k++) s += a2[k] * fc3_w[k * 4 + t];
    float g = bnf3[t], bb = bnf3[4 + t];
    float m = bnf3[8 + t], vv = bnf3[12 + t];
    s = g * (s - m) / sqrtf(vv + EPSF) + bb;  // bn BEFORE softplus here
    z[t] = softplus_f(s);
  }
  __syncthreads();
  if (t == 0) {
    float mx = fmaxf(fmaxf(z[0], z[1]), fmaxf(z[2], z[3]));
    float e0 = expf(z[0] - mx), e1 = expf(z[1] - mx);
    float e2 = expf(z[2] - mx), e3 = expf(z[3] - mx);
    float inv = 1.0f / (e0 + e1 + e2 + e3);
    out[b * 4 + 0] = e0 * inv;
    out[b * 4 + 1] = e1 * inv;
    out[b * 4 + 2] = e2 * inv;
    out[b * 4 + 3] = e3 * inv;
  }
}

extern "C" void kernel_launch(void* const* d_in, const int* in_sizes, int n_in,
                              void* d_out, int out_size, void* d_ws, size_t ws_size,
                              hipStream_t stream) {
  const float* x      = (const float*)d_in[0];
  const float* adj    = (const float*)d_in[1];
  const int*   eidx   = (const int*)d_in[2];
  const float* cheb_w = (const float*)d_in[3];
  const float* cheb_b = (const float*)d_in[4];
  const float* fc1_w  = (const float*)d_in[5];
  const float* fc1_b  = (const float*)d_in[6];
  const float* fc2_w  = (const float*)d_in[7];
  const float* fc2_b  = (const float*)d_in[8];
  const float* fc3_w  = (const float*)d_in[9];
  const float* fc3_b  = (const float*)d_in[10];
  const float* bn1    = (const float*)d_in[11];
  const float* bnf1   = (const float*)d_in[12];
  const float* bnf2   = (const float*)d_in[13];
  const float* bnf3   = (const float*)d_in[14];

  // Flat workspace (ws_size = 256 MB per harness poison fill; using ~91.5 MB, no aliasing)
  char* ws = (char*)d_ws;
  float* S    = (float*)(ws + 0);                             // 16384 B
  float* wsum = (float*)(ws + 16384);                         // 2048 B  (memset start)
  float* hc   = (float*)(ws + 18432);                         // 172032 B (memset end: 174080 B)
  unsigned short* h12  = (unsigned short*)(ws + 190464);      // 172032 B
  unsigned short* xpad = (unsigned short*)(ws + 362496);      // 22020096 B
  unsigned short* wdt  = (unsigned short*)(ws + 22382592);    // 1032192 B
  unsigned short* BThc = (unsigned short*)(ws + 23414784);    // 2064384 B
  unsigned short* Wt   = (unsigned short*)(ws + 25479168);    // 22020096 B
  unsigned short* out1 = (unsigned short*)(ws + 47499264);    // 22020096 B
  float* fc1p          = (float*)(ws + 69519360);             // 22020096 B (end ~91.5 MB)

  (void)hipMemsetAsync(ws + 16384, 0, 174080, stream);  // wsum + hc

  k_prep<<<24576, 256, 0, stream>>>(x, cheb_w, fc1_w, (unsigned int*)xpad, wdt, BThc, Wt);
  k_wsum<<<64, 256, 0, stream>>>(adj, eidx, wsum);
  k_S<<<1, 512, 0, stream>>>(eidx, wsum, S);
  k_h12f<<<21, 256, 0, stream>>>(S, x, h12);
  k_gemm_hc<<<dim3(6, 7), 256, 0, stream>>>(h12, BThc, hc);
  k_gemm_main<<<dim3(256, 6), 256, 0, stream>>>(xpad, wdt, hc, cheb_b, bn1, out1);
  k_gemm_fc1<<<dim3(2, 2, 84), 256, 0, stream>>>(out1, Wt, fc1p);
  k_final<<<256, 256, 0, stream>>>(fc1p, fc1_b, bnf1, fc2_w, fc2_b, bnf2,
                                   fc3_w, fc3_b, bnf3, (float*)d_out);
}